// Round 16
// baseline (2334.762 us; speedup 1.0000x reference)
//
#include <hip/hip_runtime.h>

typedef unsigned short u16;
typedef unsigned char u8;
typedef __bf16 bf16x8 __attribute__((ext_vector_type(8)));
typedef float f32x4 __attribute__((ext_vector_type(4)));
typedef int i32x8 __attribute__((ext_vector_type(8)));

__device__ __forceinline__ u16 f2bf(float f){
  unsigned u = __float_as_uint(f);
  unsigned r = u + 0x7FFFu + ((u >> 16) & 1u);
  return (u16)(r >> 16);
}
__device__ __forceinline__ float bf2f(u16 v){ return __uint_as_float(((unsigned)v) << 16); }

// f32 -> OCP e4m3fn, RNE, saturating (verified on-device R8-R15)
__device__ __forceinline__ u8 f2fp8(float f){
  unsigned u = __float_as_uint(f);
  u8 s = (u >> 24) & 0x80;
  float a = __uint_as_float(u & 0x7FFFFFFF);
  if (!(a < 464.f)) return s | 0x7E;
  unsigned eu = u & 0x7F800000u;
  unsigned cb = eu + (20u << 23);
  const unsigned cmin = 141u << 23;
  float c = __uint_as_float(cb > cmin ? cb : cmin);
  float q = (a + c) - c;
  if (q > 448.f) return s | 0x7E;
  if (q == 0.f) return s;
  unsigned uq = __float_as_uint(q);
  int eq = (int)(uq >> 23) - 127;
  if (eq < -6){
    int mq = (int)(q * 512.f);
    return s | (u8)mq;
  }
  return s | (u8)(((eq + 7) << 3) | ((uq >> 20) & 7));
}

__device__ __forceinline__ void gload16(const void* g, void* l){
  __builtin_amdgcn_global_load_lds(
      (const __attribute__((address_space(1))) unsigned int*)g,
      (__attribute__((address_space(3))) unsigned int*)l, 16, 0, 0);
}

// ---------------- weight transpose+convert: in f32 [K][N] -> out bf16 [N][K] ----------------
__global__ __launch_bounds__(256) void transp_k(const float* __restrict__ in, u16* __restrict__ out, int K, int N)
{
  __shared__ float tl[64][65];
  const int n0 = blockIdx.x * 64, k0 = blockIdx.y * 64;
  const int t = threadIdx.x;
  const int r = t >> 4, c4 = t & 15;
#pragma unroll
  for (int i = 0; i < 4; ++i){
    float4 v = *(const float4*)(in + (size_t)(k0 + r + i*16) * N + n0 + c4*4);
    tl[r + i*16][c4*4 + 0] = v.x; tl[r + i*16][c4*4 + 1] = v.y;
    tl[r + i*16][c4*4 + 2] = v.z; tl[r + i*16][c4*4 + 3] = v.w;
  }
  __syncthreads();
#pragma unroll
  for (int i = 0; i < 4; ++i){
    const int n = r + i*16;
    ushort4 o;
    o.x = f2bf(tl[c4*4 + 0][n]); o.y = f2bf(tl[c4*4 + 1][n]);
    o.z = f2bf(tl[c4*4 + 2][n]); o.w = f2bf(tl[c4*4 + 3][n]);
    *(ushort4*)(out + (size_t)(n0 + n) * K + k0 + c4*4) = o;
  }
}

// ---------------- weight transpose+convert: f32 [K][N] -> fp8 [N][K], scaled x16,
// PRE-SWIZZLED: (row,k) -> row*K + (k&~31) + (((k>>3)&3)^((row>>2)&3))*8 + (k&7)
__global__ __launch_bounds__(256) void transp8_k(const float* __restrict__ in, u8* __restrict__ out, int K, int N)
{
  __shared__ float tl[64][65];
  const int n0 = blockIdx.x * 64, k0 = blockIdx.y * 64;
  const int t = threadIdx.x;
  const int r = t >> 4, c4 = t & 15;
#pragma unroll
  for (int i = 0; i < 4; ++i){
    float4 v = *(const float4*)(in + (size_t)(k0 + r + i*16) * N + n0 + c4*4);
    tl[r + i*16][c4*4 + 0] = v.x; tl[r + i*16][c4*4 + 1] = v.y;
    tl[r + i*16][c4*4 + 2] = v.z; tl[r + i*16][c4*4 + 3] = v.w;
  }
  __syncthreads();
#pragma unroll
  for (int i = 0; i < 4; ++i){
    const int n = r + i*16;
    uchar4 o;
    o.x = f2fp8(tl[c4*4 + 0][n] * 16.f); o.y = f2fp8(tl[c4*4 + 1][n] * 16.f);
    o.z = f2fp8(tl[c4*4 + 2][n] * 16.f); o.w = f2fp8(tl[c4*4 + 3][n] * 16.f);
    const int ng = n0 + n;
    const int k = k0 + c4 * 4;
    const int key = (ng >> 2) & 3;
    const size_t addr = (size_t)ng * K + (k & ~31) + ((((k >> 3) & 3) ^ key) << 3) + (k & 7);
    *(uchar4*)(out + addr) = o;
  }
}

// ---------------- embedding gather ----------------
__global__ __launch_bounds__(256) void embed_k(const int* __restrict__ ids, const float* __restrict__ emb, float* __restrict__ x)
{
  const int row = blockIdx.x;
  const int c = blockIdx.y * 256 + threadIdx.x;
  x[(size_t)row * 2048 + c] = emb[(size_t)ids[row] * 2048 + c];
}

// ---------------- LayerNorm f32 -> {bf16, pre-swizzled fp8} OM: 0=bf16, 1=fp8, 2=both ----------------
template<int OM>
__global__ __launch_bounds__(256) void ln_k(const float* __restrict__ x, const float* __restrict__ gw,
                                            const float* __restrict__ bw, u16* __restrict__ o, u8* __restrict__ o8)
{
  const int row = blockIdx.x, t = threadIdx.x;
  const int lane = t & 63, wid = t >> 6;
  const float4* xr = (const float4*)(x + (size_t)row * 2048);
  float4 v1 = xr[t], v2 = xr[t + 256];
  float s1 = v1.x + v1.y + v1.z + v1.w + v2.x + v2.y + v2.z + v2.w;
  float s2 = v1.x*v1.x + v1.y*v1.y + v1.z*v1.z + v1.w*v1.w
           + v2.x*v2.x + v2.y*v2.y + v2.z*v2.z + v2.w*v2.w;
#pragma unroll
  for (int off = 32; off >= 1; off >>= 1){ s1 += __shfl_down(s1, off); s2 += __shfl_down(s2, off); }
  __shared__ float rb[2][4];
  __shared__ float mv[2];
  if (lane == 0){ rb[0][wid] = s1; rb[1][wid] = s2; }
  __syncthreads();
  if (t == 0){
    float a = rb[0][0] + rb[0][1] + rb[0][2] + rb[0][3];
    float q = rb[1][0] + rb[1][1] + rb[1][2] + rb[1][3];
    float mean = a * (1.f/2048.f);
    float var  = q * (1.f/2048.f) - mean*mean;
    mv[0] = mean; mv[1] = rsqrtf(var + 1e-5f);
  }
  __syncthreads();
  const float mean = mv[0], rstd = mv[1];
  const float4* g4 = (const float4*)gw;
  const float4* b4 = (const float4*)bw;
  float4 ga = g4[t], ba = b4[t], gb = g4[t + 256], bb2 = b4[t + 256];
  float n1x = (v1.x - mean)*rstd*ga.x + ba.x;
  float n1y = (v1.y - mean)*rstd*ga.y + ba.y;
  float n1z = (v1.z - mean)*rstd*ga.z + ba.z;
  float n1w = (v1.w - mean)*rstd*ga.w + ba.w;
  float n2x = (v2.x - mean)*rstd*gb.x + bb2.x;
  float n2y = (v2.y - mean)*rstd*gb.y + bb2.y;
  float n2z = (v2.z - mean)*rstd*gb.z + bb2.z;
  float n2w = (v2.w - mean)*rstd*gb.w + bb2.w;
  if constexpr (OM != 1){
    ushort4 o1, o2;
    o1.x = f2bf(n1x); o1.y = f2bf(n1y); o1.z = f2bf(n1z); o1.w = f2bf(n1w);
    o2.x = f2bf(n2x); o2.y = f2bf(n2y); o2.z = f2bf(n2z); o2.w = f2bf(n2w);
    ((ushort4*)(o + (size_t)row * 2048))[t] = o1;
    ((ushort4*)(o + (size_t)row * 2048))[t + 256] = o2;
  }
  if constexpr (OM != 0){
    uchar4 q1, q2;
    q1.x = f2fp8(n1x); q1.y = f2fp8(n1y); q1.z = f2fp8(n1z); q1.w = f2fp8(n1w);
    q2.x = f2fp8(n2x); q2.y = f2fp8(n2y); q2.z = f2fp8(n2z); q2.w = f2fp8(n2w);
    const int key = (row >> 2) & 3;
    const int k1 = t * 4;
    const int k2 = 1024 + t * 4;
    const int a1 = (k1 & ~31) + ((((k1 >> 3) & 3) ^ key) << 3) + (k1 & 7);
    const int a2 = (k2 & ~31) + ((((k2 >> 3) & 3) ^ key) << 3) + (k2 & 7);
    *(uchar4*)(o8 + (size_t)row * 2048 + a1) = q1;
    *(uchar4*)(o8 + (size_t)row * 2048 + a2) = q2;
  }
}

enum { M_QKV = 0, M_RES = 1, M_GELU = 2, M_LSE = 3 };

// ---------------- GEMM v2 (R2-verified): BM=128, BK=32, triple-buffer, 1 barrier/tile ----------------
template<int MODE, int BM>
__global__ __launch_bounds__(512, 2) void gemm2_k(
    const u16* __restrict__ A, const u16* __restrict__ BT,
    int N, int K, int MB,
    u16* __restrict__ outb, float* __restrict__ outf)
{
  constexpr int BK  = 32;
  constexpr int ASZ = BM * BK;
  constexpr int BSZ = 256 * BK;
  constexpr int BUF = ASZ + BSZ;
  constexpr int NFR = BM / 32;
  __shared__ u16 lds[3 * BUF];

  const int tid  = threadIdx.x;
  const int wv   = tid >> 6, lane = tid & 63;
  const int wr   = wv >> 2,  wc   = wv & 3;
  const int lg   = lane >> 4, lr  = lane & 15;

  const int nwg = gridDim.x;
  const int bid = blockIdx.x;
  const int swz = ((nwg & 7) == 0) ? ((bid & 7) * (nwg >> 3) + (bid >> 3)) : bid;
  const int bm = swz % MB, bn = swz / MB;
  const int m0 = bm * BM, n0 = bn * 256;

  const int ll = lane >> 3;
  const int cc = lane & 7;
  const int lc = cc ^ ll;
  const int gr = (ll << 1) + (lc >> 2);
  const int gk = (lc & 3) << 3;

  const u16* gA = A  + (size_t)m0 * K + gk;
  const u16* gB = BT + (size_t)n0 * K + gk;

  f32x4 acc[NFR][4];
#pragma unroll
  for (int i = 0; i < NFR; ++i)
#pragma unroll
    for (int j = 0; j < 4; ++j)
#pragma unroll
      for (int r = 0; r < 4; ++r) acc[i][j][r] = 0.f;

  const int nt = K >> 5;

  auto STAGE = [&](int bi, int kt){
    char* bA = (char*)lds + (size_t)bi * BUF * 2;
    char* bB = bA + ASZ * 2;
    const size_t ko = (size_t)kt * 32;
    gload16(gA + (size_t)(wv * 16 + gr) * K + ko, bA + wv * 1024);
    gload16(gB + (size_t)((wv    ) * 16 + gr) * K + ko, bB + (wv    ) * 1024);
    gload16(gB + (size_t)((wv + 8) * 16 + gr) * K + ko, bB + (wv + 8) * 1024);
  };

  STAGE(0, 0);
  STAGE(1, 1);

  for (int t = 0; t < nt; ++t){
    if (t + 1 < nt) asm volatile("s_waitcnt vmcnt(3) lgkmcnt(0)" ::: "memory");
    else            asm volatile("s_waitcnt vmcnt(0) lgkmcnt(0)" ::: "memory");
    __builtin_amdgcn_s_barrier();
    if (t + 2 < nt) STAGE((t + 2) % 3, t + 2);

    const char* bA = (const char*)lds + (size_t)(t % 3) * BUF * 2;
    const char* bB = bA + ASZ * 2;
    bf16x8 af[NFR], bq[4];
#pragma unroll
    for (int i = 0; i < NFR; ++i){
      const int ra = wr * (BM / 2) + i * 16 + lr;
      const int p = ra >> 1;
      const int slot = (((ra & 1) << 2) | lg) ^ (p & 7);
      af[i] = *(const bf16x8*)(bA + p * 128 + slot * 16);
    }
#pragma unroll
    for (int j = 0; j < 4; ++j){
      const int rb = wc * 64 + j * 16 + lr;
      const int p = rb >> 1;
      const int slot = (((rb & 1) << 2) | lg) ^ (p & 7);
      bq[j] = *(const bf16x8*)(bB + p * 128 + slot * 16);
    }
    __builtin_amdgcn_s_setprio(1);
#pragma unroll
    for (int i = 0; i < NFR; ++i)
#pragma unroll
      for (int j = 0; j < 4; ++j)
        acc[i][j] = __builtin_amdgcn_mfma_f32_16x16x32_bf16(af[i], bq[j], acc[i][j], 0, 0, 0);
    __builtin_amdgcn_s_setprio(0);
  }

#pragma unroll
  for (int i = 0; i < NFR; ++i){
#pragma unroll
    for (int r = 0; r < 4; ++r){
      const int row = m0 + wr * (BM / 2) + i * 16 + lg * 4 + r;
#pragma unroll
      for (int j = 0; j < 4; ++j){
        const int col = n0 + wc * 64 + j * 16 + lr;
        const float v = acc[i][j][r];
        if constexpr (MODE == M_RES){
          float* pp = outf + (size_t)row * N + col;
          *pp += v;
        } else if constexpr (MODE == M_GELU){
          float u = 0.7978845608028654f * (v + 0.044715f * v * v * v);
          u = fminf(fmaxf(u, -15.f), 15.f);
          const float ex = __expf(2.f * u);
          const float th = (ex - 1.f) / (ex + 1.f);
          outb[(size_t)row * N + col] = f2bf(0.5f * v * (1.f + th));
        }
      }
    }
  }
}

// ---------------- GEMM v6 (R6-verified): BM=BN=256, BK=64, 4-phase K-half pipeline ----------------
template<int MODE>
__global__ __launch_bounds__(512, 2) void gemm6_k(
    const u16* __restrict__ A, const u16* __restrict__ BT,
    int N, int K, int MB,
    u16* __restrict__ outb, float* __restrict__ outf, u16* __restrict__ vtout)
{
  __shared__ u16 lds[65536];

  const int tid  = threadIdx.x;
  const int wv   = tid >> 6, lane = tid & 63;
  const int wr   = wv >> 2,  wc   = wv & 3;
  const int lg   = lane >> 4, lr  = lane & 15;

  const int nwg = gridDim.x;
  const int bid = blockIdx.x;
  const int swz = ((nwg & 7) == 0) ? ((bid & 7) * (nwg >> 3) + (bid >> 3)) : bid;
  const int bm = swz % MB, bn = swz / MB;
  const int m0 = bm * 256, n0 = bn * 256;

  const int ll = lane >> 3;
  const int cc = lane & 7;
  const int lc = cc ^ ll;
  const int gr = (ll << 1) + (lc >> 2);
  const int gk = (lc & 3) << 3;

  const u16* gA = A  + (size_t)m0 * K + gk;
  const u16* gB = BT + (size_t)n0 * K + gk;

  f32x4 acc[8][4];
#pragma unroll
  for (int i = 0; i < 8; ++i)
#pragma unroll
    for (int j = 0; j < 4; ++j)
#pragma unroll
      for (int r = 0; r < 4; ++r) acc[i][j][r] = 0.f;

  const int nt = K >> 6;

  auto RB = [&](int tt, int kh, int bsel) -> char* {
    return (char*)lds + (((tt & 1) << 16) | (kh << 15) | (bsel << 14));
  };
  auto STG = [&](const u16* gsrc, int tt, int kh, int bsel){
    char* dst = RB(tt, kh, bsel);
    const size_t ko = (size_t)tt * 64 + kh * 32;
    gload16(gsrc + (size_t)((wv    ) * 16 + gr) * K + ko, dst + (wv    ) * 1024);
    gload16(gsrc + (size_t)((wv + 8) * 16 + gr) * K + ko, dst + (wv + 8) * 1024);
  };
  auto FRG = [&](int tt, int kh, int bsel, int row) -> bf16x8 {
    const int p = row >> 1;
    const int slot = (((row & 1) << 2) | lg) ^ (p & 7);
    return *(const bf16x8*)(RB(tt, kh, bsel) + p * 128 + slot * 16);
  };

  STG(gA, 0, 0, 0); STG(gB, 0, 0, 1);
  STG(gA, 0, 1, 0); STG(gB, 0, 1, 1);
  STG(gA, 1, 0, 0); STG(gB, 1, 0, 1);
  asm volatile("s_waitcnt vmcnt(4)" ::: "memory");
  __builtin_amdgcn_s_barrier();

  for (int u = 0; u < nt; ++u){
    bf16x8 bq[4], aa[4];
#pragma unroll
    for (int j = 0; j < 4; ++j) bq[j] = FRG(u, 0, 1, wc * 64 + j * 16 + lr);
#pragma unroll
    for (int i = 0; i < 4; ++i) aa[i] = FRG(u, 0, 0, wr * 128 + i * 16 + lr);
    if (u + 1 < nt) STG(gA, u + 1, 1, 0);
    __builtin_amdgcn_s_barrier();
    asm volatile("s_waitcnt lgkmcnt(0)" ::: "memory");
    __builtin_amdgcn_s_setprio(1);
#pragma unroll
    for (int i = 0; i < 4; ++i)
#pragma unroll
      for (int j = 0; j < 4; ++j)
        acc[i][j] = __builtin_amdgcn_mfma_f32_16x16x32_bf16(aa[i], bq[j], acc[i][j], 0, 0, 0);
    __builtin_amdgcn_s_setprio(0);
    __builtin_amdgcn_s_barrier();

    bf16x8 ab[4];
#pragma unroll
    for (int i = 0; i < 4; ++i) ab[i] = FRG(u, 0, 0, wr * 128 + (4 + i) * 16 + lr);
    if (u + 1 < nt) STG(gB, u + 1, 1, 1);
    __builtin_amdgcn_s_barrier();
    asm volatile("s_waitcnt lgkmcnt(0)" ::: "memory");
    __builtin_amdgcn_s_setprio(1);
#pragma unroll
    for (int i = 0; i < 4; ++i)
#pragma unroll
      for (int j = 0; j < 4; ++j)
        acc[4 + i][j] = __builtin_amdgcn_mfma_f32_16x16x32_bf16(ab[i], bq[j], acc[4 + i][j], 0, 0, 0);
    __builtin_amdgcn_s_setprio(0);
    __builtin_amdgcn_s_barrier();

    bf16x8 bq2[4], ac[4];
#pragma unroll
    for (int j = 0; j < 4; ++j) bq2[j] = FRG(u, 1, 1, wc * 64 + j * 16 + lr);
#pragma unroll
    for (int i = 0; i < 4; ++i) ac[i] = FRG(u, 1, 0, wr * 128 + i * 16 + lr);
    if (u + 2 < nt) STG(gA, u + 2, 0, 0);
    __builtin_amdgcn_s_barrier();
    asm volatile("s_waitcnt lgkmcnt(0)" ::: "memory");
    __builtin_amdgcn_s_setprio(1);
#pragma unroll
    for (int i = 0; i < 4; ++i)
#pragma unroll
      for (int j = 0; j < 4; ++j)
        acc[i][j] = __builtin_amdgcn_mfma_f32_16x16x32_bf16(ac[i], bq2[j], acc[i][j], 0, 0, 0);
    __builtin_amdgcn_s_setprio(0);
    __builtin_amdgcn_s_barrier();

    bf16x8 ad[4];
#pragma unroll
    for (int i = 0; i < 4; ++i) ad[i] = FRG(u, 1, 0, wr * 128 + (4 + i) * 16 + lr);
    if (u + 2 < nt) STG(gB, u + 2, 0, 1);
    if (u + 2 < nt)      asm volatile("s_waitcnt vmcnt(4)" ::: "memory");
    else if (u + 1 < nt) asm volatile("s_waitcnt vmcnt(0)" ::: "memory");
    __builtin_amdgcn_s_barrier();
    asm volatile("s_waitcnt lgkmcnt(0)" ::: "memory");
    __builtin_amdgcn_s_setprio(1);
#pragma unroll
    for (int i = 0; i < 4; ++i)
#pragma unroll
      for (int j = 0; j < 4; ++j)
        acc[4 + i][j] = __builtin_amdgcn_mfma_f32_16x16x32_bf16(ad[i], bq2[j], acc[4 + i][j], 0, 0, 0);
    __builtin_amdgcn_s_setprio(0);
    __builtin_amdgcn_s_barrier();
  }

#pragma unroll
  for (int i = 0; i < 8; ++i){
    if constexpr (MODE == M_QKV){
#pragma unroll
      for (int j = 0; j < 4; ++j){
        const int colb = n0 + wc * 64 + j * 16;
        if (colb < 4096){
#pragma unroll
          for (int r = 0; r < 4; ++r){
            const int row = m0 + wr * 128 + i * 16 + lg * 4 + r;
            outb[(size_t)row * 6144 + colb + lr] = f2bf(acc[i][j][r]);
          }
        } else {
          const int srow = m0 + wr * 128 + i * 16 + lg * 4;
          const int b = srow >> 10, s = srow & 1023;
          int dd = colb + lr - 4096;
          const int hh = dd >> 7; dd &= 127;
          ushort4 o;
          o.x = f2bf(acc[i][j][0]); o.y = f2bf(acc[i][j][1]);
          o.z = f2bf(acc[i][j][2]); o.w = f2bf(acc[i][j][3]);
          *(ushort4*)(vtout + ((size_t)(b * 16 + hh) * 128 + dd) * 1024 + s) = o;
        }
      }
    } else {
#pragma unroll
      for (int r = 0; r < 4; ++r){
        const int row = m0 + wr * 128 + i * 16 + lg * 4 + r;
#pragma unroll
        for (int j = 0; j < 4; ++j){
          const int col = n0 + wc * 64 + j * 16 + lr;
          const float v = acc[i][j][r];
          if constexpr (MODE == M_RES){
            float* pp = outf + (size_t)row * N + col;
            *pp += v;
          } else { // M_GELU
            float u2 = 0.7978845608028654f * (v + 0.044715f * v * v * v);
            u2 = fminf(fmaxf(u2, -15.f), 15.f);
            const float ex = __expf(2.f * u2);
            const float th = (ex - 1.f) / (ex + 1.f);
            outb[(size_t)row * N + col] = f2bf(0.5f * v * (1.f + th));
          }
        }
      }
    }
  }
}

// ---------------- GEMM v9b: MX-scaled fp8 (K=128, unit scales), BM=BN=256, BK=128,
// ring-2 x 64KB, split m-half clusters to kill spills (R15 WRITE_SIZE evidence). ----------------
template<int MODE>
__global__ __launch_bounds__(512, 2) void gemm9_k(
    const u8* __restrict__ A8, const u8* __restrict__ B8,
    int N, int K, int MB,
    u16* __restrict__ outb,
    float* __restrict__ partial, float* __restrict__ tokl,
    const int* __restrict__ ids)
{
  __shared__ u8 lds8[2 * 65536];   // 128 KB

  const int tid  = threadIdx.x;
  const int wv   = tid >> 6, lane = tid & 63;
  const int wr   = wv >> 2,  wc   = wv & 3;
  const int lg   = lane >> 4, lr  = lane & 15;

  const int nwg = gridDim.x;
  const int bid = blockIdx.x;
  const int swz = ((nwg & 7) == 0) ? ((bid & 7) * (nwg >> 3) + (bid >> 3)) : bid;
  const int bm = swz % MB, bn = swz / MB;
  const int m0 = bm * 256, n0 = bn * 256;

  const int sr = lane >> 1, sh = (lane & 1) << 4;
  const u8* gA = A8 + (size_t)(m0 + wv * 32 + sr) * K + sh;
  const u8* gB = B8 + (size_t)(n0 + wv * 32 + sr) * K + sh;

  f32x4 acc[8][4];
#pragma unroll
  for (int i = 0; i < 8; ++i)
#pragma unroll
    for (int j = 0; j < 4; ++j)
#pragma unroll
      for (int r = 0; r < 4; ++r) acc[i][j][r] = 0.f;

  const int nt = K >> 7;   // BK=128

  auto STAGE = [&](int bi, int kt){
    u8* base = lds8 + bi * 65536;
    const size_t ko = (size_t)kt * 128;
#pragma unroll
    for (int kb = 0; kb < 4; ++kb)
      gload16(gA + ko + kb * 32, base + kb * 8192 + wv * 1024);
#pragma unroll
    for (int kb = 0; kb < 4; ++kb)
      gload16(gB + ko + kb * 32, base + 32768 + kb * 8192 + wv * 1024);
  };

  auto FRX = [&](const u8* opb, int r) -> i32x8 {
    const u8* sub = opb + lg * 8192;
    const int p = r >> 2;
    i32x8 a;
#pragma unroll
    for (int c = 0; c < 4; ++c){
      const long v = *(const long*)(sub + p * 128 + ((((r & 3) << 2) | (c ^ (p & 3)))) * 8);
      a[2*c]   = (int)v;
      a[2*c+1] = (int)(v >> 32);
    }
    return a;
  };

  STAGE(0, 0);
  STAGE(1, 1);

  for (int t = 0; t < nt; ++t){
    if (t + 1 < nt) asm volatile("s_waitcnt vmcnt(8)" ::: "memory");
    else            asm volatile("s_waitcnt vmcnt(0)" ::: "memory");
    __builtin_amdgcn_s_barrier();

    const u8* bA = lds8 + (t & 1) * 65536;
    const u8* bB = bA + 32768;

    // cluster 0: B frags + first 4 A frags -> 16 MFMAs
    i32x8 bq[4], af0[4];
#pragma unroll
    for (int j = 0; j < 4; ++j) bq[j] = FRX(bB, wc * 64 + j * 16 + lr);
#pragma unroll
    for (int i = 0; i < 4; ++i) af0[i] = FRX(bA, wr * 128 + i * 16 + lr);
    __builtin_amdgcn_s_setprio(1);
#pragma unroll
    for (int i = 0; i < 4; ++i)
#pragma unroll
      for (int j = 0; j < 4; ++j)
        acc[i][j] = __builtin_amdgcn_mfma_scale_f32_16x16x128_f8f6f4(
            af0[i], bq[j], acc[i][j], 0, 0, 0, 0x7F7F7F7F, 0, 0x7F7F7F7F);
    __builtin_amdgcn_s_setprio(0);

    // cluster 1: last 4 A frags (reads drained before restage barrier)
    i32x8 af1[4];
#pragma unroll
    for (int i = 0; i < 4; ++i) af1[i] = FRX(bA, wr * 128 + (4 + i) * 16 + lr);
    asm volatile("s_waitcnt lgkmcnt(0)" ::: "memory");
    __builtin_amdgcn_s_barrier();

    if (t + 2 < nt) STAGE(t & 1, t + 2);

    __builtin_amdgcn_s_setprio(1);
#pragma unroll
    for (int i = 0; i < 4; ++i)
#pragma unroll
      for (int j = 0; j < 4; ++j)
        acc[4 + i][j] = __builtin_amdgcn_mfma_scale_f32_16x16x128_f8f6f4(
            af1[i], bq[j], acc[4 + i][j], 0, 0, 0, 0x7F7F7F7F, 0, 0x7F7F7F7F);
    __builtin_amdgcn_s_setprio(0);
  }

  // epilogues: weights were scaled x16, undo with 1/16
#pragma unroll
  for (int i = 0; i < 8; ++i){
    if constexpr (MODE == M_LSE){
#pragma unroll
      for (int r = 0; r < 4; ++r){
        const int row = m0 + wr * 128 + i * 16 + lg * 4 + r;
        const int id = ids[row];
        float esum = 0.f;
#pragma unroll
        for (int j = 0; j < 4; ++j){
          const int col = n0 + wc * 64 + j * 16 + lr;
          const float v = acc[i][j][r] * 0.0625f;
          if (col == id) tokl[row] = v;
          esum += __expf(v);
        }
#pragma unroll
        for (int off = 8; off >= 1; off >>= 1) esum += __shfl_xor(esum, off);
        if (lr == 0) partial[(size_t)row * 500 + bn * 4 + wc] = esum;
      }
    } else { // M_GELU
#pragma unroll
      for (int r = 0; r < 4; ++r){
        const int row = m0 + wr * 128 + i * 16 + lg * 4 + r;
#pragma unroll
        for (int j = 0; j < 4; ++j){
          const int col = n0 + wc * 64 + j * 16 + lr;
          const float v = acc[i][j][r] * 0.0625f;
          float u = 0.7978845608028654f * (v + 0.044715f * v * v * v);
          u = fminf(fmaxf(u, -15.f), 15.f);
          const float ex = __expf(2.f * u);
          const float th = (ex - 1.f) / (ex + 1.f);
          outb[(size_t)row * N + col] = f2bf(0.5f * v * (1.f + th));
        }
      }
    }
  }
}

// ---------------- flash attention (causal), 1 wave / 16 q-rows ----------------
__global__ __launch_bounds__(64) void attn_k(const u16* __restrict__ qkv, const u16* __restrict__ vT, u16* __restrict__ o16)
{
  __shared__ u16 P[16 * 40];
  const int bid = blockIdx.x;
  const int qt = bid & 63, bh = bid >> 6;
  const int h = bh & 15, b = bh >> 4;
  const int lane = threadIdx.x, lg = lane >> 4, lr = lane & 15;
  const int q0 = qt << 4;
  const u16* qrow  = qkv + (size_t)(b * 1024 + q0 + lr) * 6144 + h * 128;
  const u16* krow  = qkv + (size_t)(b * 1024 + lr) * 6144 + 2048 + h * 128;
  const u16* vbase = vT + (size_t)(b * 16 + h) * 128 * 1024;

  bf16x8 qf[4];
#pragma unroll
  for (int c = 0; c < 4; ++c) qf[c] = *(const bf16x8*)(qrow + c * 32 + lg * 8);

  float m[4], l[4];
  f32x4 oacc[8];
#pragma unroll
  for (int r = 0; r < 4; ++r){ m[r] = -1e30f; l[r] = 0.f; }
#pragma unroll
  for (int f = 0; f < 8; ++f)
#pragma unroll
    for (int r = 0; r < 4; ++r) oacc[f][r] = 0.f;

  const float scale = 0.08838834764831845f;
  const int nk2 = (qt >> 1) + 1;
  for (int k2 = 0; k2 < nk2; ++k2){
    float e[2][4];
    float rmax[4];
#pragma unroll
    for (int r = 0; r < 4; ++r) rmax[r] = -1e30f;
#pragma unroll
    for (int hh = 0; hh < 2; ++hh){
      const int kt = k2 * 2 + hh;
      if (kt <= qt){
        f32x4 s;
#pragma unroll
        for (int r = 0; r < 4; ++r) s[r] = 0.f;
#pragma unroll
        for (int c = 0; c < 4; ++c){
          bf16x8 kf = *(const bf16x8*)(krow + (size_t)(kt * 16) * 6144 + c * 32 + lg * 8);
          s = __builtin_amdgcn_mfma_f32_16x16x32_bf16(qf[c], kf, s, 0, 0, 0);
        }
#pragma unroll
        for (int r = 0; r < 4; ++r){
          float sv = s[r] * scale;
          if (kt * 16 + lr > q0 + lg * 4 + r) sv = -1e30f;
          e[hh][r] = sv;
          rmax[r] = fmaxf(rmax[r], sv);
        }
      } else {
#pragma unroll
        for (int r = 0; r < 4; ++r) e[hh][r] = -1e30f;
      }
    }
#pragma unroll
    for (int off = 8; off >= 1; off >>= 1)
#pragma unroll
      for (int r = 0; r < 4; ++r) rmax[r] = fmaxf(rmax[r], __shfl_xor(rmax[r], off));
    float corr[4], rsum[4];
#pragma unroll
    for (int r = 0; r < 4; ++r){
      const float mn = fmaxf(m[r], rmax[r]);
      corr[r] = __expf(m[r] - mn);
      m[r] = mn;
      const float e0 = __expf(e[0][r] - mn);
      const float e1 = __expf(e[1][r] - mn);
      e[0][r] = e0; e[1][r] = e1;
      rsum[r] = e0 + e1;
    }
#pragma unroll
    for (int off = 8; off >= 1; off >>= 1)
#pragma unroll
      for (int r = 0; r < 4; ++r) rsum[r] += __shfl_xor(rsum[r], off);
#pragma unroll
    for (int r = 0; r < 4; ++r) l[r] = l[r] * corr[r] + rsum[r];
#pragma unroll
    for (int hh = 0; hh < 2; ++hh)
#pragma unroll
      for (int r = 0; r < 4; ++r)
        P[(lg * 4 + r) * 40 + hh * 16 + lr] = f2bf(e[hh][r]);
#pragma unroll
    for (int f = 0; f < 8; ++f)
#pragma unroll
      for (int r = 0; r < 4; ++r) oacc[f][r] = oacc[f][r] * corr[r];
    __syncthreads();
    const bf16x8 pa = *(const bf16x8*)((const u16*)P + lr * 40 + lg * 8);
#pragma unroll
    for (int f = 0; f < 8; ++f){
      bf16x8 vb = *(const bf16x8*)(vbase + (size_t)(f * 16 + lr) * 1024 + k2 * 32 + lg * 8);
      oacc[f] = __builtin_amdgcn_mfma_f32_16x16x32_bf16(pa, vb, oacc[f], 0, 0, 0);
    }
    __syncthreads();
  }
  u16* orow = o16 + (size_t)(b * 1024 + q0 + lg * 4) * 2048 + h * 128;
#pragma unroll
  for (int r = 0; r < 4; ++r){
    const float linv = 1.0f / l[r];
#pragma unroll
    for (int f = 0; f < 8; ++f)
      orow[(size_t)r * 2048 + f * 16 + lr] = f2bf(oacc[f][r] * linv);
  }
}

// ---------------- logsumexp finalize + surprisal ----------------
__global__ __launch_bounds__(256) void lse_k(const float* __restrict__ partial, const float* __restrict__ tokl,
                                             const int* __restrict__ amask, float* __restrict__ surp)
{
  const int row = blockIdx.x, t = threadIdx.x, lane = t & 63, wid = t >> 6;
  float s = 0.f;
  if (t < 250) s = partial[(size_t)row * 500 + t] + partial[(size_t)row * 500 + t + 250];
#pragma unroll
  for (int off = 32; off >= 1; off >>= 1) s += __shfl_down(s, off);
  __shared__ float rb[4];
  if (lane == 0) rb[wid] = s;
  __syncthreads();
  if (t == 0){
    const float tot = rb[0] + rb[1] + rb[2] + rb[3];
    surp[row] = (logf(tot) - tokl[row]) * 1.4426950408889634f * (float)amask[row];
  }
}

// ---------------- mean-pool over sequence ----------------
__global__ __launch_bounds__(256) void pool_k(const u16* __restrict__ h16, float* __restrict__ pooled)
{
  const int d = blockIdx.x * 256 + threadIdx.x;
  const int b = blockIdx.y;
  const u16* p = h16 + (size_t)b * 1024 * 2048 + d;
  float a0 = 0.f, a1 = 0.f, a2 = 0.f, a3 = 0.f;
  for (int s = 0; s < 1024; s += 4){
    a0 += bf2f(p[(size_t)(s + 0) * 2048]);
    a1 += bf2f(p[(size_t)(s + 1) * 2048]);
    a2 += bf2f(p[(size_t)(s + 2) * 2048]);
    a3 += bf2f(p[(size_t)(s + 3) * 2048]);
  }
  pooled[b * 2048 + d] = (a0 + a1 + a2 + a3) * (1.f / 1024.f);
}

// ---------------- classifier head ----------------
__global__ __launch_bounds__(256) void cls_k(const float* __restrict__ pooled, const float* __restrict__ surp,
                                             const int* __restrict__ amask, const float* __restrict__ sent,
                                             const float* __restrict__ ppl, const float* __restrict__ redw,
                                             const float* __restrict__ redb, const float* __restrict__ clsw,
                                             const float* __restrict__ clsb, float* __restrict__ out)
{
  const int b = blockIdx.x, t = threadIdx.x;
  const int lane = t & 63, wid = t >> 6;
  __shared__ float pl[2048];
  __shared__ float feats[112];
  __shared__ float rbuf[2][4];
#pragma unroll
  for (int i = 0; i < 8; ++i) pl[t + i * 256] = pooled[b * 2048 + t + i * 256];
  float ssum = 0.f, msum = 0.f;
#pragma unroll
  for (int i = 0; i < 4; ++i){
    const int s = t + i * 256;
    ssum += surp[b * 1024 + s];
    msum += (float)amask[b * 1024 + s];
  }
#pragma unroll
  for (int off = 32; off >= 1; off >>= 1){ ssum += __shfl_down(ssum, off); msum += __shfl_down(msum, off); }
  if (lane == 0){ rbuf[0][wid] = ssum; rbuf[1][wid] = msum; }
  __syncthreads();
  if (t == 0){
    float a = 0.f, c = 0.f;
    for (int i = 0; i < 4; ++i){ a += rbuf[0][i]; c += rbuf[1][i]; }
    feats[104] = a / c;
  }
  if (t >= 100 && t < 103) feats[t] = sent[b * 3 + (t - 100)];
  if (t == 103) feats[103] = ppl[b];
  if (t < 100){
    float a = redb[t];
    for (int d = 0; d < 2048; ++d) a += pl[d] * redw[d * 100 + t];
    feats[t] = (a > 0.f) ? a : 0.01f * a;
  }
  __syncthreads();
  if (t < 3){
    float a = clsb[t];
    for (int i = 0; i < 105; ++i) a += feats[i] * clsw[i * 3 + t];
    out[b * 3 + t] = a;
  }
}

// ---------------- host launch ----------------
extern "C" void kernel_launch(void* const* d_in, const int* in_sizes, int n_in,
                              void* d_out, int out_size, void* d_ws, size_t ws_size,
                              hipStream_t stream)
{
  (void)in_sizes; (void)n_in; (void)out_size; (void)ws_size;
  const int*   ids   = (const int*)d_in[0];
  const int*   amask = (const int*)d_in[1];
  const float* sent  = (const float*)d_in[2];
  const float* ppl   = (const float*)d_in[3];
  const float* emb   = (const float*)d_in[4];
  const float* ln1g  = (const float*)d_in[5];
  const float* ln1b  = (const float*)d_in[6];
  const float* qkvw  = (const float*)d_in[7];
  const float* wow   = (const float*)d_in[8];
  const float* ln2g  = (const float*)d_in[9];
  const float* ln2b  = (const float*)d_in[10];
  const float* w1    = (const float*)d_in[11];
  const float* w2    = (const float*)d_in[12];
  const float* lnfg  = (const float*)d_in[13];
  const float* lnfb  = (const float*)d_in[14];
  const float* headw = (const float*)d_in[15];
  const float* redw  = (const float*)d_in[16];
  const float* redb  = (const float*)d_in[17];
  const float* clsw  = (const float*)d_in[18];
  const float* clsb  = (const float*)d_in[19];
  float* out = (float*)d_out;

  char* p = (char*)d_ws;
  u16* wqkvT = (u16*)p; p += (size_t)2 * 6144 * 2048 * 2;
  u16* woT   = (u16*)p; p += (size_t)2 * 2048 * 2048 * 2;
  u8*  w18   = (u8*)p;  p += (size_t)2 * 8192 * 2048;
  u16* w2T   = (u16*)p; p += (size_t)2 * 2048 * 8192 * 2;
  u8*  wh8   = (u8*)p;  p += (size_t)32000 * 2048;
  float* xbuf = (float*)p; p += (size_t)4096 * 2048 * 4;
  u16* h16   = (u16*)p; p += (size_t)4096 * 2048 * 2;
  u8*  h8    = (u8*)p;  p += (size_t)4096 * 2048;
  u16* qkv16 = (u16*)p;
  u16* vT16  = (u16*)(p + (size_t)4096 * 6144 * 2);
  u16* ffn16 = (u16*)p;
  p += (size_t)4096 * 6144 * 2 + (size_t)4096 * 2048 * 2;
  u16* o16   = (u16*)p; p += (size_t)4096 * 2048 * 2;
  float* partial = (float*)p; p += (size_t)4096 * 500 * 4;
  float* tokl = (float*)p; p += (size_t)4096 * 4;
  float* surp = (float*)p; p += (size_t)4096 * 4;
  float* pooled = (float*)p; p += (size_t)4 * 2048 * 4;

  for (int l = 0; l < 2; ++l){
    transp_k<<<dim3(6144/64, 2048/64), 256, 0, stream>>>(qkvw + (size_t)l*2048*6144, wqkvT + (size_t)l*6144*2048, 2048, 6144);
    transp_k<<<dim3(2048/64, 2048/64), 256, 0, stream>>>(wow  + (size_t)l*2048*2048, woT   + (size_t)l*2048*2048, 2048, 2048);
    transp8_k<<<dim3(8192/64, 2048/64), 256, 0, stream>>>(w1   + (size_t)l*2048*8192, w18   + (size_t)l*8192*2048, 2048, 8192);
    transp_k<<<dim3(2048/64, 8192/64), 256, 0, stream>>>(w2   + (size_t)l*8192*2048, w2T   + (size_t)l*2048*8192, 8192, 2048);
  }
  transp8_k<<<dim3(32000/64, 2048/64), 256, 0, stream>>>(headw, wh8, 2048, 32000);

  embed_k<<<dim3(4096, 8), 256, 0, stream>>>(ids, emb, xbuf);

  for (int l = 0; l < 2; ++l){
    ln_k<0><<<4096, 256, 0, stream>>>(xbuf, ln1g + l*2048, ln1b + l*2048, h16, nullptr);
    gemm6_k<M_QKV><<<16*24, 512, 0, stream>>>(h16, wqkvT + (size_t)l*6144*2048, 6144, 2048, 16,
                                              qkv16, nullptr, vT16);
    attn_k<<<4096, 64, 0, stream>>>(qkv16, vT16, o16);
    gemm2_k<M_RES,128><<<32*8, 512, 0, stream>>>(o16, woT + (size_t)l*2048*2048, 2048, 2048, 32,
                                                 nullptr, xbuf);
    ln_k<1><<<4096, 256, 0, stream>>>(xbuf, ln2g + l*2048, ln2b + l*2048, nullptr, h8);
    gemm9_k<M_GELU><<<16*32, 512, 0, stream>>>(h8, w18 + (size_t)l*8192*2048, 8192, 2048, 16,
                                               ffn16, nullptr, nullptr, nullptr);
    gemm2_k<M_RES,128><<<32*8, 512, 0, stream>>>(ffn16, w2T + (size_t)l*2048*8192, 2048, 8192, 32,
                                                 nullptr, xbuf);
  }
  ln_k<2><<<4096, 256, 0, stream>>>(xbuf, lnfg, lnfb, h16, h8);
  gemm9_k<M_LSE><<<16*125, 512, 0, stream>>>(h8, wh8, 32000, 2048, 16,
                                             nullptr, partial, tokl, ids);
  lse_k<<<4096, 256, 0, stream>>>(partial, tokl, amask, surp);
  pool_k<<<dim3(8, 4), 256, 0, stream>>>(h16, pooled);
  cls_k<<<4, 256, 0, stream>>>(pooled, surp, amask, sent, ppl, redw, redb, clsw, clsb, out);
}

// Round 17
// 2241.226 us; speedup vs baseline: 1.0417x; 1.0417x over previous
//
#include <hip/hip_runtime.h>

typedef unsigned short u16;
typedef unsigned char u8;
typedef __bf16 bf16x8 __attribute__((ext_vector_type(8)));
typedef float f32x4 __attribute__((ext_vector_type(4)));

__device__ __forceinline__ u16 f2bf(float f){
  unsigned u = __float_as_uint(f);
  unsigned r = u + 0x7FFFu + ((u >> 16) & 1u);
  return (u16)(r >> 16);
}
__device__ __forceinline__ float bf2f(u16 v){ return __uint_as_float(((unsigned)v) << 16); }

// f32 -> OCP e4m3fn, RNE, saturating (verified on-device R8-R16)
__device__ __forceinline__ u8 f2fp8(float f){
  unsigned u = __float_as_uint(f);
  u8 s = (u >> 24) & 0x80;
  float a = __uint_as_float(u & 0x7FFFFFFF);
  if (!(a < 464.f)) return s | 0x7E;
  unsigned eu = u & 0x7F800000u;
  unsigned cb = eu + (20u << 23);
  const unsigned cmin = 141u << 23;
  float c = __uint_as_float(cb > cmin ? cb : cmin);
  float q = (a + c) - c;
  if (q > 448.f) return s | 0x7E;
  if (q == 0.f) return s;
  unsigned uq = __float_as_uint(q);
  int eq = (int)(uq >> 23) - 127;
  if (eq < -6){
    int mq = (int)(q * 512.f);
    return s | (u8)mq;
  }
  return s | (u8)(((eq + 7) << 3) | ((uq >> 20) & 7));
}

__device__ __forceinline__ void gload16(const void* g, void* l){
  __builtin_amdgcn_global_load_lds(
      (const __attribute__((address_space(1))) unsigned int*)g,
      (__attribute__((address_space(3))) unsigned int*)l, 16, 0, 0);
}

// ---------------- weight transpose+convert: in f32 [K][N] -> out bf16 [N][K] ----------------
__global__ __launch_bounds__(256) void transp_k(const float* __restrict__ in, u16* __restrict__ out, int K, int N)
{
  __shared__ float tl[64][65];
  const int n0 = blockIdx.x * 64, k0 = blockIdx.y * 64;
  const int t = threadIdx.x;
  const int r = t >> 4, c4 = t & 15;
#pragma unroll
  for (int i = 0; i < 4; ++i){
    float4 v = *(const float4*)(in + (size_t)(k0 + r + i*16) * N + n0 + c4*4);
    tl[r + i*16][c4*4 + 0] = v.x; tl[r + i*16][c4*4 + 1] = v.y;
    tl[r + i*16][c4*4 + 2] = v.z; tl[r + i*16][c4*4 + 3] = v.w;
  }
  __syncthreads();
#pragma unroll
  for (int i = 0; i < 4; ++i){
    const int n = r + i*16;
    ushort4 o;
    o.x = f2bf(tl[c4*4 + 0][n]); o.y = f2bf(tl[c4*4 + 1][n]);
    o.z = f2bf(tl[c4*4 + 2][n]); o.w = f2bf(tl[c4*4 + 3][n]);
    *(ushort4*)(out + (size_t)(n0 + n) * K + k0 + c4*4) = o;
  }
}

// ---------------- weight transpose+convert: f32 [K][N] -> fp8 [N][K], scaled x16,
// PRE-SWIZZLED: (row,k) -> row*K + (k&~31) + (((k>>3)&3)^((row>>2)&3))*8 + (k&7)
__global__ __launch_bounds__(256) void transp8_k(const float* __restrict__ in, u8* __restrict__ out, int K, int N)
{
  __shared__ float tl[64][65];
  const int n0 = blockIdx.x * 64, k0 = blockIdx.y * 64;
  const int t = threadIdx.x;
  const int r = t >> 4, c4 = t & 15;
#pragma unroll
  for (int i = 0; i < 4; ++i){
    float4 v = *(const float4*)(in + (size_t)(k0 + r + i*16) * N + n0 + c4*4);
    tl[r + i*16][c4*4 + 0] = v.x; tl[r + i*16][c4*4 + 1] = v.y;
    tl[r + i*16][c4*4 + 2] = v.z; tl[r + i*16][c4*4 + 3] = v.w;
  }
  __syncthreads();
#pragma unroll
  for (int i = 0; i < 4; ++i){
    const int n = r + i*16;
    uchar4 o;
    o.x = f2fp8(tl[c4*4 + 0][n] * 16.f); o.y = f2fp8(tl[c4*4 + 1][n] * 16.f);
    o.z = f2fp8(tl[c4*4 + 2][n] * 16.f); o.w = f2fp8(tl[c4*4 + 3][n] * 16.f);
    const int ng = n0 + n;
    const int k = k0 + c4 * 4;
    const int key = (ng >> 2) & 3;
    const size_t addr = (size_t)ng * K + (k & ~31) + ((((k >> 3) & 3) ^ key) << 3) + (k & 7);
    *(uchar4*)(out + addr) = o;
  }
}

// ---------------- embedding gather ----------------
__global__ __launch_bounds__(256) void embed_k(const int* __restrict__ ids, const float* __restrict__ emb, float* __restrict__ x)
{
  const int row = blockIdx.x;
  const int c = blockIdx.y * 256 + threadIdx.x;
  x[(size_t)row * 2048 + c] = emb[(size_t)ids[row] * 2048 + c];
}

// ---------------- LayerNorm f32 -> {bf16, pre-swizzled fp8} OM: 0=bf16, 1=fp8, 2=both ----------------
template<int OM>
__global__ __launch_bounds__(256) void ln_k(const float* __restrict__ x, const float* __restrict__ gw,
                                            const float* __restrict__ bw, u16* __restrict__ o, u8* __restrict__ o8)
{
  const int row = blockIdx.x, t = threadIdx.x;
  const int lane = t & 63, wid = t >> 6;
  const float4* xr = (const float4*)(x + (size_t)row * 2048);
  float4 v1 = xr[t], v2 = xr[t + 256];
  float s1 = v1.x + v1.y + v1.z + v1.w + v2.x + v2.y + v2.z + v2.w;
  float s2 = v1.x*v1.x + v1.y*v1.y + v1.z*v1.z + v1.w*v1.w
           + v2.x*v2.x + v2.y*v2.y + v2.z*v2.z + v2.w*v2.w;
#pragma unroll
  for (int off = 32; off >= 1; off >>= 1){ s1 += __shfl_down(s1, off); s2 += __shfl_down(s2, off); }
  __shared__ float rb[2][4];
  __shared__ float mv[2];
  if (lane == 0){ rb[0][wid] = s1; rb[1][wid] = s2; }
  __syncthreads();
  if (t == 0){
    float a = rb[0][0] + rb[0][1] + rb[0][2] + rb[0][3];
    float q = rb[1][0] + rb[1][1] + rb[1][2] + rb[1][3];
    float mean = a * (1.f/2048.f);
    float var  = q * (1.f/2048.f) - mean*mean;
    mv[0] = mean; mv[1] = rsqrtf(var + 1e-5f);
  }
  __syncthreads();
  const float mean = mv[0], rstd = mv[1];
  const float4* g4 = (const float4*)gw;
  const float4* b4 = (const float4*)bw;
  float4 ga = g4[t], ba = b4[t], gb = g4[t + 256], bb2 = b4[t + 256];
  float n1x = (v1.x - mean)*rstd*ga.x + ba.x;
  float n1y = (v1.y - mean)*rstd*ga.y + ba.y;
  float n1z = (v1.z - mean)*rstd*ga.z + ba.z;
  float n1w = (v1.w - mean)*rstd*ga.w + ba.w;
  float n2x = (v2.x - mean)*rstd*gb.x + bb2.x;
  float n2y = (v2.y - mean)*rstd*gb.y + bb2.y;
  float n2z = (v2.z - mean)*rstd*gb.z + bb2.z;
  float n2w = (v2.w - mean)*rstd*gb.w + bb2.w;
  if constexpr (OM != 1){
    ushort4 o1, o2;
    o1.x = f2bf(n1x); o1.y = f2bf(n1y); o1.z = f2bf(n1z); o1.w = f2bf(n1w);
    o2.x = f2bf(n2x); o2.y = f2bf(n2y); o2.z = f2bf(n2z); o2.w = f2bf(n2w);
    ((ushort4*)(o + (size_t)row * 2048))[t] = o1;
    ((ushort4*)(o + (size_t)row * 2048))[t + 256] = o2;
  }
  if constexpr (OM != 0){
    uchar4 q1, q2;
    q1.x = f2fp8(n1x); q1.y = f2fp8(n1y); q1.z = f2fp8(n1z); q1.w = f2fp8(n1w);
    q2.x = f2fp8(n2x); q2.y = f2fp8(n2y); q2.z = f2fp8(n2z); q2.w = f2fp8(n2w);
    const int key = (row >> 2) & 3;
    const int k1 = t * 4;
    const int k2 = 1024 + t * 4;
    const int a1 = (k1 & ~31) + ((((k1 >> 3) & 3) ^ key) << 3) + (k1 & 7);
    const int a2 = (k2 & ~31) + ((((k2 >> 3) & 3) ^ key) << 3) + (k2 & 7);
    *(uchar4*)(o8 + (size_t)row * 2048 + a1) = q1;
    *(uchar4*)(o8 + (size_t)row * 2048 + a2) = q2;
  }
}

enum { M_QKV = 0, M_RES = 1, M_GELU = 2, M_LSE = 3 };

// ---------------- GEMM v2 (R2-verified): BM=128, BK=32, triple-buffer, 1 barrier/tile ----------------
template<int MODE, int BM>
__global__ __launch_bounds__(512, 2) void gemm2_k(
    const u16* __restrict__ A, const u16* __restrict__ BT,
    int N, int K, int MB,
    u16* __restrict__ outb, float* __restrict__ outf)
{
  constexpr int BK  = 32;
  constexpr int ASZ = BM * BK;
  constexpr int BSZ = 256 * BK;
  constexpr int BUF = ASZ + BSZ;
  constexpr int NFR = BM / 32;
  __shared__ u16 lds[3 * BUF];

  const int tid  = threadIdx.x;
  const int wv   = tid >> 6, lane = tid & 63;
  const int wr   = wv >> 2,  wc   = wv & 3;
  const int lg   = lane >> 4, lr  = lane & 15;

  const int nwg = gridDim.x;
  const int bid = blockIdx.x;
  const int swz = ((nwg & 7) == 0) ? ((bid & 7) * (nwg >> 3) + (bid >> 3)) : bid;
  const int bm = swz % MB, bn = swz / MB;
  const int m0 = bm * BM, n0 = bn * 256;

  const int ll = lane >> 3;
  const int cc = lane & 7;
  const int lc = cc ^ ll;
  const int gr = (ll << 1) + (lc >> 2);
  const int gk = (lc & 3) << 3;

  const u16* gA = A  + (size_t)m0 * K + gk;
  const u16* gB = BT + (size_t)n0 * K + gk;

  f32x4 acc[NFR][4];
#pragma unroll
  for (int i = 0; i < NFR; ++i)
#pragma unroll
    for (int j = 0; j < 4; ++j)
#pragma unroll
      for (int r = 0; r < 4; ++r) acc[i][j][r] = 0.f;

  const int nt = K >> 5;

  auto STAGE = [&](int bi, int kt){
    char* bA = (char*)lds + (size_t)bi * BUF * 2;
    char* bB = bA + ASZ * 2;
    const size_t ko = (size_t)kt * 32;
    gload16(gA + (size_t)(wv * 16 + gr) * K + ko, bA + wv * 1024);
    gload16(gB + (size_t)((wv    ) * 16 + gr) * K + ko, bB + (wv    ) * 1024);
    gload16(gB + (size_t)((wv + 8) * 16 + gr) * K + ko, bB + (wv + 8) * 1024);
  };

  STAGE(0, 0);
  STAGE(1, 1);

  for (int t = 0; t < nt; ++t){
    if (t + 1 < nt) asm volatile("s_waitcnt vmcnt(3) lgkmcnt(0)" ::: "memory");
    else            asm volatile("s_waitcnt vmcnt(0) lgkmcnt(0)" ::: "memory");
    __builtin_amdgcn_s_barrier();
    if (t + 2 < nt) STAGE((t + 2) % 3, t + 2);

    const char* bA = (const char*)lds + (size_t)(t % 3) * BUF * 2;
    const char* bB = bA + ASZ * 2;
    bf16x8 af[NFR], bq[4];
#pragma unroll
    for (int i = 0; i < NFR; ++i){
      const int ra = wr * (BM / 2) + i * 16 + lr;
      const int p = ra >> 1;
      const int slot = (((ra & 1) << 2) | lg) ^ (p & 7);
      af[i] = *(const bf16x8*)(bA + p * 128 + slot * 16);
    }
#pragma unroll
    for (int j = 0; j < 4; ++j){
      const int rb = wc * 64 + j * 16 + lr;
      const int p = rb >> 1;
      const int slot = (((rb & 1) << 2) | lg) ^ (p & 7);
      bq[j] = *(const bf16x8*)(bB + p * 128 + slot * 16);
    }
    __builtin_amdgcn_s_setprio(1);
#pragma unroll
    for (int i = 0; i < NFR; ++i)
#pragma unroll
      for (int j = 0; j < 4; ++j)
        acc[i][j] = __builtin_amdgcn_mfma_f32_16x16x32_bf16(af[i], bq[j], acc[i][j], 0, 0, 0);
    __builtin_amdgcn_s_setprio(0);
  }

#pragma unroll
  for (int i = 0; i < NFR; ++i){
#pragma unroll
    for (int r = 0; r < 4; ++r){
      const int row = m0 + wr * (BM / 2) + i * 16 + lg * 4 + r;
#pragma unroll
      for (int j = 0; j < 4; ++j){
        const int col = n0 + wc * 64 + j * 16 + lr;
        const float v = acc[i][j][r];
        if constexpr (MODE == M_RES){
          float* pp = outf + (size_t)row * N + col;
          *pp += v;
        } else if constexpr (MODE == M_GELU){
          float u = 0.7978845608028654f * (v + 0.044715f * v * v * v);
          u = fminf(fmaxf(u, -15.f), 15.f);
          const float ex = __expf(2.f * u);
          const float th = (ex - 1.f) / (ex + 1.f);
          outb[(size_t)row * N + col] = f2bf(0.5f * v * (1.f + th));
        }
      }
    }
  }
}

// ---------------- GEMM v6 (R6-verified): BM=BN=256, BK=64, 4-phase K-half pipeline ----------------
template<int MODE>
__global__ __launch_bounds__(512, 2) void gemm6_k(
    const u16* __restrict__ A, const u16* __restrict__ BT,
    int N, int K, int MB,
    u16* __restrict__ outb, float* __restrict__ outf, u16* __restrict__ vtout)
{
  __shared__ u16 lds[65536];

  const int tid  = threadIdx.x;
  const int wv   = tid >> 6, lane = tid & 63;
  const int wr   = wv >> 2,  wc   = wv & 3;
  const int lg   = lane >> 4, lr  = lane & 15;

  const int nwg = gridDim.x;
  const int bid = blockIdx.x;
  const int swz = ((nwg & 7) == 0) ? ((bid & 7) * (nwg >> 3) + (bid >> 3)) : bid;
  const int bm = swz % MB, bn = swz / MB;
  const int m0 = bm * 256, n0 = bn * 256;

  const int ll = lane >> 3;
  const int cc = lane & 7;
  const int lc = cc ^ ll;
  const int gr = (ll << 1) + (lc >> 2);
  const int gk = (lc & 3) << 3;

  const u16* gA = A  + (size_t)m0 * K + gk;
  const u16* gB = BT + (size_t)n0 * K + gk;

  f32x4 acc[8][4];
#pragma unroll
  for (int i = 0; i < 8; ++i)
#pragma unroll
    for (int j = 0; j < 4; ++j)
#pragma unroll
      for (int r = 0; r < 4; ++r) acc[i][j][r] = 0.f;

  const int nt = K >> 6;

  auto RB = [&](int tt, int kh, int bsel) -> char* {
    return (char*)lds + (((tt & 1) << 16) | (kh << 15) | (bsel << 14));
  };
  auto STG = [&](const u16* gsrc, int tt, int kh, int bsel){
    char* dst = RB(tt, kh, bsel);
    const size_t ko = (size_t)tt * 64 + kh * 32;
    gload16(gsrc + (size_t)((wv    ) * 16 + gr) * K + ko, dst + (wv    ) * 1024);
    gload16(gsrc + (size_t)((wv + 8) * 16 + gr) * K + ko, dst + (wv + 8) * 1024);
  };
  auto FRG = [&](int tt, int kh, int bsel, int row) -> bf16x8 {
    const int p = row >> 1;
    const int slot = (((row & 1) << 2) | lg) ^ (p & 7);
    return *(const bf16x8*)(RB(tt, kh, bsel) + p * 128 + slot * 16);
  };

  STG(gA, 0, 0, 0); STG(gB, 0, 0, 1);
  STG(gA, 0, 1, 0); STG(gB, 0, 1, 1);
  STG(gA, 1, 0, 0); STG(gB, 1, 0, 1);
  asm volatile("s_waitcnt vmcnt(4)" ::: "memory");
  __builtin_amdgcn_s_barrier();

  for (int u = 0; u < nt; ++u){
    bf16x8 bq[4], aa[4];
#pragma unroll
    for (int j = 0; j < 4; ++j) bq[j] = FRG(u, 0, 1, wc * 64 + j * 16 + lr);
#pragma unroll
    for (int i = 0; i < 4; ++i) aa[i] = FRG(u, 0, 0, wr * 128 + i * 16 + lr);
    if (u + 1 < nt) STG(gA, u + 1, 1, 0);
    __builtin_amdgcn_s_barrier();
    asm volatile("s_waitcnt lgkmcnt(0)" ::: "memory");
    __builtin_amdgcn_s_setprio(1);
#pragma unroll
    for (int i = 0; i < 4; ++i)
#pragma unroll
      for (int j = 0; j < 4; ++j)
        acc[i][j] = __builtin_amdgcn_mfma_f32_16x16x32_bf16(aa[i], bq[j], acc[i][j], 0, 0, 0);
    __builtin_amdgcn_s_setprio(0);
    __builtin_amdgcn_s_barrier();

    bf16x8 ab[4];
#pragma unroll
    for (int i = 0; i < 4; ++i) ab[i] = FRG(u, 0, 0, wr * 128 + (4 + i) * 16 + lr);
    if (u + 1 < nt) STG(gB, u + 1, 1, 1);
    __builtin_amdgcn_s_barrier();
    asm volatile("s_waitcnt lgkmcnt(0)" ::: "memory");
    __builtin_amdgcn_s_setprio(1);
#pragma unroll
    for (int i = 0; i < 4; ++i)
#pragma unroll
      for (int j = 0; j < 4; ++j)
        acc[4 + i][j] = __builtin_amdgcn_mfma_f32_16x16x32_bf16(ab[i], bq[j], acc[4 + i][j], 0, 0, 0);
    __builtin_amdgcn_s_setprio(0);
    __builtin_amdgcn_s_barrier();

    bf16x8 bq2[4], ac[4];
#pragma unroll
    for (int j = 0; j < 4; ++j) bq2[j] = FRG(u, 1, 1, wc * 64 + j * 16 + lr);
#pragma unroll
    for (int i = 0; i < 4; ++i) ac[i] = FRG(u, 1, 0, wr * 128 + i * 16 + lr);
    if (u + 2 < nt) STG(gA, u + 2, 0, 0);
    __builtin_amdgcn_s_barrier();
    asm volatile("s_waitcnt lgkmcnt(0)" ::: "memory");
    __builtin_amdgcn_s_setprio(1);
#pragma unroll
    for (int i = 0; i < 4; ++i)
#pragma unroll
      for (int j = 0; j < 4; ++j)
        acc[i][j] = __builtin_amdgcn_mfma_f32_16x16x32_bf16(ac[i], bq2[j], acc[i][j], 0, 0, 0);
    __builtin_amdgcn_s_setprio(0);
    __builtin_amdgcn_s_barrier();

    bf16x8 ad[4];
#pragma unroll
    for (int i = 0; i < 4; ++i) ad[i] = FRG(u, 1, 0, wr * 128 + (4 + i) * 16 + lr);
    if (u + 2 < nt) STG(gB, u + 2, 0, 1);
    if (u + 2 < nt)      asm volatile("s_waitcnt vmcnt(4)" ::: "memory");
    else if (u + 1 < nt) asm volatile("s_waitcnt vmcnt(0)" ::: "memory");
    __builtin_amdgcn_s_barrier();
    asm volatile("s_waitcnt lgkmcnt(0)" ::: "memory");
    __builtin_amdgcn_s_setprio(1);
#pragma unroll
    for (int i = 0; i < 4; ++i)
#pragma unroll
      for (int j = 0; j < 4; ++j)
        acc[4 + i][j] = __builtin_amdgcn_mfma_f32_16x16x32_bf16(ad[i], bq2[j], acc[4 + i][j], 0, 0, 0);
    __builtin_amdgcn_s_setprio(0);
    __builtin_amdgcn_s_barrier();
  }

#pragma unroll
  for (int i = 0; i < 8; ++i){
    if constexpr (MODE == M_QKV){
#pragma unroll
      for (int j = 0; j < 4; ++j){
        const int colb = n0 + wc * 64 + j * 16;
        if (colb < 4096){
#pragma unroll
          for (int r = 0; r < 4; ++r){
            const int row = m0 + wr * 128 + i * 16 + lg * 4 + r;
            outb[(size_t)row * 6144 + colb + lr] = f2bf(acc[i][j][r]);
          }
        } else {
          const int srow = m0 + wr * 128 + i * 16 + lg * 4;
          const int b = srow >> 10, s = srow & 1023;
          int dd = colb + lr - 4096;
          const int hh = dd >> 7; dd &= 127;
          ushort4 o;
          o.x = f2bf(acc[i][j][0]); o.y = f2bf(acc[i][j][1]);
          o.z = f2bf(acc[i][j][2]); o.w = f2bf(acc[i][j][3]);
          *(ushort4*)(vtout + ((size_t)(b * 16 + hh) * 128 + dd) * 1024 + s) = o;
        }
      }
    } else {
#pragma unroll
      for (int r = 0; r < 4; ++r){
        const int row = m0 + wr * 128 + i * 16 + lg * 4 + r;
#pragma unroll
        for (int j = 0; j < 4; ++j){
          const int col = n0 + wc * 64 + j * 16 + lr;
          const float v = acc[i][j][r];
          if constexpr (MODE == M_RES){
            float* pp = outf + (size_t)row * N + col;
            *pp += v;
          } else { // M_GELU
            float u2 = 0.7978845608028654f * (v + 0.044715f * v * v * v);
            u2 = fminf(fmaxf(u2, -15.f), 15.f);
            const float ex = __expf(2.f * u2);
            const float th = (ex - 1.f) / (ex + 1.f);
            outb[(size_t)row * N + col] = f2bf(0.5f * v * (1.f + th));
          }
        }
      }
    }
  }
}

// ---------------- GEMM v8 (R12-verified): fp8, BM=BN=256, BK=32, pre-swizzled sources,
// linear global_load_lds staging, conflict-free ds_read_b64, epilogues GELU/LSE ----------------
template<int MODE>
__global__ __launch_bounds__(512, 2) void gemm8_k(
    const u8* __restrict__ A8, const u8* __restrict__ B8,
    int N, int K, int MB,
    u16* __restrict__ outb,
    float* __restrict__ partial, float* __restrict__ tokl,
    const int* __restrict__ ids)
{
  __shared__ u8 lds8[2 * 16384];

  const int tid  = threadIdx.x;
  const int wv   = tid >> 6, lane = tid & 63;
  const int wr   = wv >> 2,  wc   = wv & 3;
  const int lg   = lane >> 4, lr  = lane & 15;

  const int nwg = gridDim.x;
  const int bid = blockIdx.x;
  const int swz = ((nwg & 7) == 0) ? ((bid & 7) * (nwg >> 3) + (bid >> 3)) : bid;
  const int bm = swz % MB, bn = swz / MB;
  const int m0 = bm * 256, n0 = bn * 256;

  const int sr = lane >> 1, sh = (lane & 1) << 4;
  const u8* gA = A8 + (size_t)(m0 + wv * 32 + sr) * K + sh;
  const u8* gB = B8 + (size_t)(n0 + wv * 32 + sr) * K + sh;

  f32x4 acc[8][4];
#pragma unroll
  for (int i = 0; i < 8; ++i)
#pragma unroll
    for (int j = 0; j < 4; ++j)
#pragma unroll
      for (int r = 0; r < 4; ++r) acc[i][j][r] = 0.f;

  const int nt = K >> 5;

  auto STAGE = [&](int bi, int kt){
    u8* base = lds8 + bi * 16384;
    gload16(gA + (size_t)kt * 32, base + wv * 1024);
    gload16(gB + (size_t)kt * 32, base + 8192 + wv * 1024);
  };

  auto FR8 = [&](const u8* base, int r) -> long {
    const int p = r >> 2;
    const int g = ((r & 3) << 2) | (lg ^ (p & 3));
    return *(const long*)(base + p * 128 + g * 8);
  };

  STAGE(0, 0);
  STAGE(1, 1);

  for (int t = 0; t < nt; ++t){
    if (t + 1 < nt) asm volatile("s_waitcnt vmcnt(2)" ::: "memory");
    else            asm volatile("s_waitcnt vmcnt(0)" ::: "memory");
    __builtin_amdgcn_s_barrier();

    const u8* bA = lds8 + (t & 1) * 16384;
    const u8* bB = bA + 8192;
    long af[8], bq[4];
#pragma unroll
    for (int i = 0; i < 8; ++i) af[i] = FR8(bA, wr * 128 + i * 16 + lr);
#pragma unroll
    for (int j = 0; j < 4; ++j) bq[j] = FR8(bB, wc * 64 + j * 16 + lr);
    asm volatile("s_waitcnt lgkmcnt(0)" ::: "memory");
    __builtin_amdgcn_s_barrier();

    if (t + 2 < nt) STAGE(t & 1, t + 2);

    __builtin_amdgcn_s_setprio(1);
#pragma unroll
    for (int i = 0; i < 8; ++i)
#pragma unroll
      for (int j = 0; j < 4; ++j)
        acc[i][j] = __builtin_amdgcn_mfma_f32_16x16x32_fp8_fp8(af[i], bq[j], acc[i][j], 0, 0, 0);
    __builtin_amdgcn_s_setprio(0);
  }

  // epilogues: weights were scaled x16, undo with 1/16
#pragma unroll
  for (int i = 0; i < 8; ++i){
    if constexpr (MODE == M_LSE){
#pragma unroll
      for (int r = 0; r < 4; ++r){
        const int row = m0 + wr * 128 + i * 16 + lg * 4 + r;
        const int id = ids[row];
        float esum = 0.f;
#pragma unroll
        for (int j = 0; j < 4; ++j){
          const int col = n0 + wc * 64 + j * 16 + lr;
          const float v = acc[i][j][r] * 0.0625f;
          if (col == id) tokl[row] = v;
          esum += __expf(v);
        }
#pragma unroll
        for (int off = 8; off >= 1; off >>= 1) esum += __shfl_xor(esum, off);
        if (lr == 0) partial[(size_t)row * 500 + bn * 4 + wc] = esum;
      }
    } else { // M_GELU
#pragma unroll
      for (int r = 0; r < 4; ++r){
        const int row = m0 + wr * 128 + i * 16 + lg * 4 + r;
#pragma unroll
        for (int j = 0; j < 4; ++j){
          const int col = n0 + wc * 64 + j * 16 + lr;
          const float v = acc[i][j][r] * 0.0625f;
          float u = 0.7978845608028654f * (v + 0.044715f * v * v * v);
          u = fminf(fmaxf(u, -15.f), 15.f);
          const float ex = __expf(2.f * u);
          const float th = (ex - 1.f) / (ex + 1.f);
          outb[(size_t)row * N + col] = f2bf(0.5f * v * (1.f + th));
        }
      }
    }
  }
}

// ---------------- flash attention (causal), 1 wave / 16 q-rows ----------------
__global__ __launch_bounds__(64) void attn_k(const u16* __restrict__ qkv, const u16* __restrict__ vT, u16* __restrict__ o16)
{
  __shared__ u16 P[16 * 40];
  const int bid = blockIdx.x;
  const int qt = bid & 63, bh = bid >> 6;
  const int h = bh & 15, b = bh >> 4;
  const int lane = threadIdx.x, lg = lane >> 4, lr = lane & 15;
  const int q0 = qt << 4;
  const u16* qrow  = qkv + (size_t)(b * 1024 + q0 + lr) * 6144 + h * 128;
  const u16* krow  = qkv + (size_t)(b * 1024 + lr) * 6144 + 2048 + h * 128;
  const u16* vbase = vT + (size_t)(b * 16 + h) * 128 * 1024;

  bf16x8 qf[4];
#pragma unroll
  for (int c = 0; c < 4; ++c) qf[c] = *(const bf16x8*)(qrow + c * 32 + lg * 8);

  float m[4], l[4];
  f32x4 oacc[8];
#pragma unroll
  for (int r = 0; r < 4; ++r){ m[r] = -1e30f; l[r] = 0.f; }
#pragma unroll
  for (int f = 0; f < 8; ++f)
#pragma unroll
    for (int r = 0; r < 4; ++r) oacc[f][r] = 0.f;

  const float scale = 0.08838834764831845f;
  const int nk2 = (qt >> 1) + 1;
  for (int k2 = 0; k2 < nk2; ++k2){
    float e[2][4];
    float rmax[4];
#pragma unroll
    for (int r = 0; r < 4; ++r) rmax[r] = -1e30f;
#pragma unroll
    for (int hh = 0; hh < 2; ++hh){
      const int kt = k2 * 2 + hh;
      if (kt <= qt){
        f32x4 s;
#pragma unroll
        for (int r = 0; r < 4; ++r) s[r] = 0.f;
#pragma unroll
        for (int c = 0; c < 4; ++c){
          bf16x8 kf = *(const bf16x8*)(krow + (size_t)(kt * 16) * 6144 + c * 32 + lg * 8);
          s = __builtin_amdgcn_mfma_f32_16x16x32_bf16(qf[c], kf, s, 0, 0, 0);
        }
#pragma unroll
        for (int r = 0; r < 4; ++r){
          float sv = s[r] * scale;
          if (kt * 16 + lr > q0 + lg * 4 + r) sv = -1e30f;
          e[hh][r] = sv;
          rmax[r] = fmaxf(rmax[r], sv);
        }
      } else {
#pragma unroll
        for (int r = 0; r < 4; ++r) e[hh][r] = -1e30f;
      }
    }
#pragma unroll
    for (int off = 8; off >= 1; off >>= 1)
#pragma unroll
      for (int r = 0; r < 4; ++r) rmax[r] = fmaxf(rmax[r], __shfl_xor(rmax[r], off));
    float corr[4], rsum[4];
#pragma unroll
    for (int r = 0; r < 4; ++r){
      const float mn = fmaxf(m[r], rmax[r]);
      corr[r] = __expf(m[r] - mn);
      m[r] = mn;
      const float e0 = __expf(e[0][r] - mn);
      const float e1 = __expf(e[1][r] - mn);
      e[0][r] = e0; e[1][r] = e1;
      rsum[r] = e0 + e1;
    }
#pragma unroll
    for (int off = 8; off >= 1; off >>= 1)
#pragma unroll
      for (int r = 0; r < 4; ++r) rsum[r] += __shfl_xor(rsum[r], off);
#pragma unroll
    for (int r = 0; r < 4; ++r) l[r] = l[r] * corr[r] + rsum[r];
#pragma unroll
    for (int hh = 0; hh < 2; ++hh)
#pragma unroll
      for (int r = 0; r < 4; ++r)
        P[(lg * 4 + r) * 40 + hh * 16 + lr] = f2bf(e[hh][r]);
#pragma unroll
    for (int f = 0; f < 8; ++f)
#pragma unroll
      for (int r = 0; r < 4; ++r) oacc[f][r] = oacc[f][r] * corr[r];
    __syncthreads();
    const bf16x8 pa = *(const bf16x8*)((const u16*)P + lr * 40 + lg * 8);
#pragma unroll
    for (int f = 0; f < 8; ++f){
      bf16x8 vb = *(const bf16x8*)(vbase + (size_t)(f * 16 + lr) * 1024 + k2 * 32 + lg * 8);
      oacc[f] = __builtin_amdgcn_mfma_f32_16x16x32_bf16(pa, vb, oacc[f], 0, 0, 0);
    }
    __syncthreads();
  }
  u16* orow = o16 + (size_t)(b * 1024 + q0 + lg * 4) * 2048 + h * 128;
#pragma unroll
  for (int r = 0; r < 4; ++r){
    const float linv = 1.0f / l[r];
#pragma unroll
    for (int f = 0; f < 8; ++f)
      orow[(size_t)r * 2048 + f * 16 + lr] = f2bf(oacc[f][r] * linv);
  }
}

// ---------------- logsumexp finalize + surprisal ----------------
__global__ __launch_bounds__(256) void lse_k(const float* __restrict__ partial, const float* __restrict__ tokl,
                                             const int* __restrict__ amask, float* __restrict__ surp)
{
  const int row = blockIdx.x, t = threadIdx.x, lane = t & 63, wid = t >> 6;
  float s = 0.f;
  if (t < 250) s = partial[(size_t)row * 500 + t] + partial[(size_t)row * 500 + t + 250];
#pragma unroll
  for (int off = 32; off >= 1; off >>= 1) s += __shfl_down(s, off);
  __shared__ float rb[4];
  if (lane == 0) rb[wid] = s;
  __syncthreads();
  if (t == 0){
    const float tot = rb[0] + rb[1] + rb[2] + rb[3];
    surp[row] = (logf(tot) - tokl[row]) * 1.4426950408889634f * (float)amask[row];
  }
}

// ---------------- mean-pool over sequence ----------------
__global__ __launch_bounds__(256) void pool_k(const u16* __restrict__ h16, float* __restrict__ pooled)
{
  const int d = blockIdx.x * 256 + threadIdx.x;
  const int b = blockIdx.y;
  const u16* p = h16 + (size_t)b * 1024 * 2048 + d;
  float a0 = 0.f, a1 = 0.f, a2 = 0.f, a3 = 0.f;
  for (int s = 0; s < 1024; s += 4){
    a0 += bf2f(p[(size_t)(s + 0) * 2048]);
    a1 += bf2f(p[(size_t)(s + 1) * 2048]);
    a2 += bf2f(p[(size_t)(s + 2) * 2048]);
    a3 += bf2f(p[(size_t)(s + 3) * 2048]);
  }
  pooled[b * 2048 + d] = (a0 + a1 + a2 + a3) * (1.f / 1024.f);
}

// ---------------- classifier head ----------------
__global__ __launch_bounds__(256) void cls_k(const float* __restrict__ pooled, const float* __restrict__ surp,
                                             const int* __restrict__ amask, const float* __restrict__ sent,
                                             const float* __restrict__ ppl, const float* __restrict__ redw,
                                             const float* __restrict__ redb, const float* __restrict__ clsw,
                                             const float* __restrict__ clsb, float* __restrict__ out)
{
  const int b = blockIdx.x, t = threadIdx.x;
  const int lane = t & 63, wid = t >> 6;
  __shared__ float pl[2048];
  __shared__ float feats[112];
  __shared__ float rbuf[2][4];
#pragma unroll
  for (int i = 0; i < 8; ++i) pl[t + i * 256] = pooled[b * 2048 + t + i * 256];
  float ssum = 0.f, msum = 0.f;
#pragma unroll
  for (int i = 0; i < 4; ++i){
    const int s = t + i * 256;
    ssum += surp[b * 1024 + s];
    msum += (float)amask[b * 1024 + s];
  }
#pragma unroll
  for (int off = 32; off >= 1; off >>= 1){ ssum += __shfl_down(ssum, off); msum += __shfl_down(msum, off); }
  if (lane == 0){ rbuf[0][wid] = ssum; rbuf[1][wid] = msum; }
  __syncthreads();
  if (t == 0){
    float a = 0.f, c = 0.f;
    for (int i = 0; i < 4; ++i){ a += rbuf[0][i]; c += rbuf[1][i]; }
    feats[104] = a / c;
  }
  if (t >= 100 && t < 103) feats[t] = sent[b * 3 + (t - 100)];
  if (t == 103) feats[103] = ppl[b];
  if (t < 100){
    float a = redb[t];
    for (int d = 0; d < 2048; ++d) a += pl[d] * redw[d * 100 + t];
    feats[t] = (a > 0.f) ? a : 0.01f * a;
  }
  __syncthreads();
  if (t < 3){
    float a = clsb[t];
    for (int i = 0; i < 105; ++i) a += feats[i] * clsw[i * 3 + t];
    out[b * 3 + t] = a;
  }
}

// ---------------- host launch ----------------
extern "C" void kernel_launch(void* const* d_in, const int* in_sizes, int n_in,
                              void* d_out, int out_size, void* d_ws, size_t ws_size,
                              hipStream_t stream)
{
  (void)in_sizes; (void)n_in; (void)out_size; (void)ws_size;
  const int*   ids   = (const int*)d_in[0];
  const int*   amask = (const int*)d_in[1];
  const float* sent  = (const float*)d_in[2];
  const float* ppl   = (const float*)d_in[3];
  const float* emb   = (const float*)d_in[4];
  const float* ln1g  = (const float*)d_in[5];
  const float* ln1b  = (const float*)d_in[6];
  const float* qkvw  = (const float*)d_in[7];
  const float* wow   = (const float*)d_in[8];
  const float* ln2g  = (const float*)d_in[9];
  const float* ln2b  = (const float*)d_in[10];
  const float* w1    = (const float*)d_in[11];
  const float* w2    = (const float*)d_in[12];
  const float* lnfg  = (const float*)d_in[13];
  const float* lnfb  = (const float*)d_in[14];
  const float* headw = (const float*)d_in[15];
  const float* redw  = (const float*)d_in[16];
  const float* redb  = (const float*)d_in[17];
  const float* clsw  = (const float*)d_in[18];
  const float* clsb  = (const float*)d_in[19];
  float* out = (float*)d_out;

  char* p = (char*)d_ws;
  u16* wqkvT = (u16*)p; p += (size_t)2 * 6144 * 2048 * 2;
  u16* woT   = (u16*)p; p += (size_t)2 * 2048 * 2048 * 2;
  u8*  w18   = (u8*)p;  p += (size_t)2 * 8192 * 2048;
  u16* w2T   = (u16*)p; p += (size_t)2 * 2048 * 8192 * 2;
  u8*  wh8   = (u8*)p;  p += (size_t)32000 * 2048;
  float* xbuf = (float*)p; p += (size_t)4096 * 2048 * 4;
  u16* h16   = (u16*)p; p += (size_t)4096 * 2048 * 2;
  u8*  h8    = (u8*)p;  p += (size_t)4096 * 2048;
  u16* qkv16 = (u16*)p;
  u16* vT16  = (u16*)(p + (size_t)4096 * 6144 * 2);
  u16* ffn16 = (u16*)p;
  p += (size_t)4096 * 6144 * 2 + (size_t)4096 * 2048 * 2;
  u16* o16   = (u16*)p; p += (size_t)4096 * 2048 * 2;
  float* partial = (float*)p; p += (size_t)4096 * 500 * 4;
  float* tokl = (float*)p; p += (size_t)4096 * 4;
  float* surp = (float*)p; p += (size_t)4096 * 4;
  float* pooled = (float*)p; p += (size_t)4 * 2048 * 4;

  for (int l = 0; l < 2; ++l){
    transp_k<<<dim3(6144/64, 2048/64), 256, 0, stream>>>(qkvw + (size_t)l*2048*6144, wqkvT + (size_t)l*6144*2048, 2048, 6144);
    transp_k<<<dim3(2048/64, 2048/64), 256, 0, stream>>>(wow  + (size_t)l*2048*2048, woT   + (size_t)l*2048*2048, 2048, 2048);
    transp8_k<<<dim3(8192/64, 2048/64), 256, 0, stream>>>(w1   + (size_t)l*2048*8192, w18   + (size_t)l*8192*2048, 2048, 8192);
    transp_k<<<dim3(2048/64, 8192/64), 256, 0, stream>>>(w2   + (size_t)l*8192*2048, w2T   + (size_t)l*2048*8192, 8192, 2048);
  }
  transp8_k<<<dim3(32000/64, 2048/64), 256, 0, stream>>>(headw, wh8, 2048, 32000);

  embed_k<<<dim3(4096, 8), 256, 0, stream>>>(ids, emb, xbuf);

  for (int l = 0; l < 2; ++l){
    ln_k<0><<<4096, 256, 0, stream>>>(xbuf, ln1g + l*2048, ln1b + l*2048, h16, nullptr);
    gemm6_k<M_QKV><<<16*24, 512, 0, stream>>>(h16, wqkvT + (size_t)l*6144*2048, 6144, 2048, 16,
                                              qkv16, nullptr, vT16);
    attn_k<<<4096, 64, 0, stream>>>(qkv16, vT16, o16);
    gemm2_k<M_RES,128><<<32*8, 512, 0, stream>>>(o16, woT + (size_t)l*2048*2048, 2048, 2048, 32,
                                                 nullptr, xbuf);
    ln_k<1><<<4096, 256, 0, stream>>>(xbuf, ln2g + l*2048, ln2b + l*2048, nullptr, h8);
    gemm8_k<M_GELU><<<16*32, 512, 0, stream>>>(h8, w18 + (size_t)l*8192*2048, 8192, 2048, 16,
                                               ffn16, nullptr, nullptr, nullptr);
    gemm2_k<M_RES,128><<<32*8, 512, 0, stream>>>(ffn16, w2T + (size_t)l*2048*8192, 2048, 8192, 32,
                                                 nullptr, xbuf);
  }
  ln_k<2><<<4096, 256, 0, stream>>>(xbuf, lnfg, lnfb, h16, h8);
  gemm8_k<M_LSE><<<16*125, 512, 0, stream>>>(h8, wh8, 32000, 2048, 16,
                                             nullptr, partial, tokl, ids);
  lse_k<<<4096, 256, 0, stream>>>(partial, tokl, amask, surp);
  pool_k<<<dim3(8, 4), 256, 0, stream>>>(h16, pooled);
  cls_k<<<4, 256, 0, stream>>>(pooled, surp, amask, sent, ppl, redw, redb, clsw, clsb, out);
}

// Round 18
// 2139.632 us; speedup vs baseline: 1.0912x; 1.0475x over previous
//
#include <hip/hip_runtime.h>

typedef unsigned short u16;
typedef unsigned char u8;
typedef __bf16 bf16x8 __attribute__((ext_vector_type(8)));
typedef float f32x4 __attribute__((ext_vector_type(4)));

__device__ __forceinline__ u16 f2bf(float f){
  unsigned u = __float_as_uint(f);
  unsigned r = u + 0x7FFFu + ((u >> 16) & 1u);
  return (u16)(r >> 16);
}
__device__ __forceinline__ float bf2f(u16 v){ return __uint_as_float(((unsigned)v) << 16); }

// f32 -> OCP e4m3fn, RNE, saturating (verified on-device R8-R17)
__device__ __forceinline__ u8 f2fp8(float f){
  unsigned u = __float_as_uint(f);
  u8 s = (u >> 24) & 0x80;
  float a = __uint_as_float(u & 0x7FFFFFFF);
  if (!(a < 464.f)) return s | 0x7E;
  unsigned eu = u & 0x7F800000u;
  unsigned cb = eu + (20u << 23);
  const unsigned cmin = 141u << 23;
  float c = __uint_as_float(cb > cmin ? cb : cmin);
  float q = (a + c) - c;
  if (q > 448.f) return s | 0x7E;
  if (q == 0.f) return s;
  unsigned uq = __float_as_uint(q);
  int eq = (int)(uq >> 23) - 127;
  if (eq < -6){
    int mq = (int)(q * 512.f);
    return s | (u8)mq;
  }
  return s | (u8)(((eq + 7) << 3) | ((uq >> 20) & 7));
}

__device__ __forceinline__ void gload16(const void* g, void* l){
  __builtin_amdgcn_global_load_lds(
      (const __attribute__((address_space(1))) unsigned int*)g,
      (__attribute__((address_space(3))) unsigned int*)l, 16, 0, 0);
}

// ---------------- weight transpose+convert: in f32 [K][N] -> out bf16 [N][K] ----------------
__global__ __launch_bounds__(256) void transp_k(const float* __restrict__ in, u16* __restrict__ out, int K, int N)
{
  __shared__ float tl[64][65];
  const int n0 = blockIdx.x * 64, k0 = blockIdx.y * 64;
  const int t = threadIdx.x;
  const int r = t >> 4, c4 = t & 15;
#pragma unroll
  for (int i = 0; i < 4; ++i){
    float4 v = *(const float4*)(in + (size_t)(k0 + r + i*16) * N + n0 + c4*4);
    tl[r + i*16][c4*4 + 0] = v.x; tl[r + i*16][c4*4 + 1] = v.y;
    tl[r + i*16][c4*4 + 2] = v.z; tl[r + i*16][c4*4 + 3] = v.w;
  }
  __syncthreads();
#pragma unroll
  for (int i = 0; i < 4; ++i){
    const int n = r + i*16;
    ushort4 o;
    o.x = f2bf(tl[c4*4 + 0][n]); o.y = f2bf(tl[c4*4 + 1][n]);
    o.z = f2bf(tl[c4*4 + 2][n]); o.w = f2bf(tl[c4*4 + 3][n]);
    *(ushort4*)(out + (size_t)(n0 + n) * K + k0 + c4*4) = o;
  }
}

// ---------------- weight transpose+convert: f32 [K][N] -> fp8 [N][K], scaled x16,
// PRE-SWIZZLED: (row,k) -> row*K + (k&~31) + (((k>>3)&3)^((row>>2)&3))*8 + (k&7)
__global__ __launch_bounds__(256) void transp8_k(const float* __restrict__ in, u8* __restrict__ out, int K, int N)
{
  __shared__ float tl[64][65];
  const int n0 = blockIdx.x * 64, k0 = blockIdx.y * 64;
  const int t = threadIdx.x;
  const int r = t >> 4, c4 = t & 15;
#pragma unroll
  for (int i = 0; i < 4; ++i){
    float4 v = *(const float4*)(in + (size_t)(k0 + r + i*16) * N + n0 + c4*4);
    tl[r + i*16][c4*4 + 0] = v.x; tl[r + i*16][c4*4 + 1] = v.y;
    tl[r + i*16][c4*4 + 2] = v.z; tl[r + i*16][c4*4 + 3] = v.w;
  }
  __syncthreads();
#pragma unroll
  for (int i = 0; i < 4; ++i){
    const int n = r + i*16;
    uchar4 o;
    o.x = f2fp8(tl[c4*4 + 0][n] * 16.f); o.y = f2fp8(tl[c4*4 + 1][n] * 16.f);
    o.z = f2fp8(tl[c4*4 + 2][n] * 16.f); o.w = f2fp8(tl[c4*4 + 3][n] * 16.f);
    const int ng = n0 + n;
    const int k = k0 + c4 * 4;
    const int key = (ng >> 2) & 3;
    const size_t addr = (size_t)ng * K + (k & ~31) + ((((k >> 3) & 3) ^ key) << 3) + (k & 7);
    *(uchar4*)(out + addr) = o;
  }
}

// ---------------- embedding gather ----------------
__global__ __launch_bounds__(256) void embed_k(const int* __restrict__ ids, const float* __restrict__ emb, float* __restrict__ x)
{
  const int row = blockIdx.x;
  const int c = blockIdx.y * 256 + threadIdx.x;
  x[(size_t)row * 2048 + c] = emb[(size_t)ids[row] * 2048 + c];
}

// ---------------- LayerNorm f32 -> {bf16, pre-swizzled fp8} OM: 0=bf16, 1=fp8, 2=both ----------------
template<int OM>
__global__ __launch_bounds__(256) void ln_k(const float* __restrict__ x, const float* __restrict__ gw,
                                            const float* __restrict__ bw, u16* __restrict__ o, u8* __restrict__ o8)
{
  const int row = blockIdx.x, t = threadIdx.x;
  const int lane = t & 63, wid = t >> 6;
  const float4* xr = (const float4*)(x + (size_t)row * 2048);
  float4 v1 = xr[t], v2 = xr[t + 256];
  float s1 = v1.x + v1.y + v1.z + v1.w + v2.x + v2.y + v2.z + v2.w;
  float s2 = v1.x*v1.x + v1.y*v1.y + v1.z*v1.z + v1.w*v1.w
           + v2.x*v2.x + v2.y*v2.y + v2.z*v2.z + v2.w*v2.w;
#pragma unroll
  for (int off = 32; off >= 1; off >>= 1){ s1 += __shfl_down(s1, off); s2 += __shfl_down(s2, off); }
  __shared__ float rb[2][4];
  __shared__ float mv[2];
  if (lane == 0){ rb[0][wid] = s1; rb[1][wid] = s2; }
  __syncthreads();
  if (t == 0){
    float a = rb[0][0] + rb[0][1] + rb[0][2] + rb[0][3];
    float q = rb[1][0] + rb[1][1] + rb[1][2] + rb[1][3];
    float mean = a * (1.f/2048.f);
    float var  = q * (1.f/2048.f) - mean*mean;
    mv[0] = mean; mv[1] = rsqrtf(var + 1e-5f);
  }
  __syncthreads();
  const float mean = mv[0], rstd = mv[1];
  const float4* g4 = (const float4*)gw;
  const float4* b4 = (const float4*)bw;
  float4 ga = g4[t], ba = b4[t], gb = g4[t + 256], bb2 = b4[t + 256];
  float n1x = (v1.x - mean)*rstd*ga.x + ba.x;
  float n1y = (v1.y - mean)*rstd*ga.y + ba.y;
  float n1z = (v1.z - mean)*rstd*ga.z + ba.z;
  float n1w = (v1.w - mean)*rstd*ga.w + ba.w;
  float n2x = (v2.x - mean)*rstd*gb.x + bb2.x;
  float n2y = (v2.y - mean)*rstd*gb.y + bb2.y;
  float n2z = (v2.z - mean)*rstd*gb.z + bb2.z;
  float n2w = (v2.w - mean)*rstd*gb.w + bb2.w;
  if constexpr (OM != 1){
    ushort4 o1, o2;
    o1.x = f2bf(n1x); o1.y = f2bf(n1y); o1.z = f2bf(n1z); o1.w = f2bf(n1w);
    o2.x = f2bf(n2x); o2.y = f2bf(n2y); o2.z = f2bf(n2z); o2.w = f2bf(n2w);
    ((ushort4*)(o + (size_t)row * 2048))[t] = o1;
    ((ushort4*)(o + (size_t)row * 2048))[t + 256] = o2;
  }
  if constexpr (OM != 0){
    uchar4 q1, q2;
    q1.x = f2fp8(n1x); q1.y = f2fp8(n1y); q1.z = f2fp8(n1z); q1.w = f2fp8(n1w);
    q2.x = f2fp8(n2x); q2.y = f2fp8(n2y); q2.z = f2fp8(n2z); q2.w = f2fp8(n2w);
    const int key = (row >> 2) & 3;
    const int k1 = t * 4;
    const int k2 = 1024 + t * 4;
    const int a1 = (k1 & ~31) + ((((k1 >> 3) & 3) ^ key) << 3) + (k1 & 7);
    const int a2 = (k2 & ~31) + ((((k2 >> 3) & 3) ^ key) << 3) + (k2 & 7);
    *(uchar4*)(o8 + (size_t)row * 2048 + a1) = q1;
    *(uchar4*)(o8 + (size_t)row * 2048 + a2) = q2;
  }
}

enum { M_QKV = 0, M_RES = 1, M_GELU = 2, M_LSE = 3 };

// ---------------- GEMM v2 (R2-verified): BM=128, BK=32, triple-buffer, 1 barrier/tile ----------------
template<int MODE, int BM>
__global__ __launch_bounds__(512, 2) void gemm2_k(
    const u16* __restrict__ A, const u16* __restrict__ BT,
    int N, int K, int MB,
    u16* __restrict__ outb, float* __restrict__ outf)
{
  constexpr int BK  = 32;
  constexpr int ASZ = BM * BK;
  constexpr int BSZ = 256 * BK;
  constexpr int BUF = ASZ + BSZ;
  constexpr int NFR = BM / 32;
  __shared__ u16 lds[3 * BUF];

  const int tid  = threadIdx.x;
  const int wv   = tid >> 6, lane = tid & 63;
  const int wr   = wv >> 2,  wc   = wv & 3;
  const int lg   = lane >> 4, lr  = lane & 15;

  const int nwg = gridDim.x;
  const int bid = blockIdx.x;
  const int swz = ((nwg & 7) == 0) ? ((bid & 7) * (nwg >> 3) + (bid >> 3)) : bid;
  const int bm = swz % MB, bn = swz / MB;
  const int m0 = bm * BM, n0 = bn * 256;

  const int ll = lane >> 3;
  const int cc = lane & 7;
  const int lc = cc ^ ll;
  const int gr = (ll << 1) + (lc >> 2);
  const int gk = (lc & 3) << 3;

  const u16* gA = A  + (size_t)m0 * K + gk;
  const u16* gB = BT + (size_t)n0 * K + gk;

  f32x4 acc[NFR][4];
#pragma unroll
  for (int i = 0; i < NFR; ++i)
#pragma unroll
    for (int j = 0; j < 4; ++j)
#pragma unroll
      for (int r = 0; r < 4; ++r) acc[i][j][r] = 0.f;

  const int nt = K >> 5;

  auto STAGE = [&](int bi, int kt){
    char* bA = (char*)lds + (size_t)bi * BUF * 2;
    char* bB = bA + ASZ * 2;
    const size_t ko = (size_t)kt * 32;
    gload16(gA + (size_t)(wv * 16 + gr) * K + ko, bA + wv * 1024);
    gload16(gB + (size_t)((wv    ) * 16 + gr) * K + ko, bB + (wv    ) * 1024);
    gload16(gB + (size_t)((wv + 8) * 16 + gr) * K + ko, bB + (wv + 8) * 1024);
  };

  STAGE(0, 0);
  STAGE(1, 1);

  for (int t = 0; t < nt; ++t){
    if (t + 1 < nt) asm volatile("s_waitcnt vmcnt(3) lgkmcnt(0)" ::: "memory");
    else            asm volatile("s_waitcnt vmcnt(0) lgkmcnt(0)" ::: "memory");
    __builtin_amdgcn_s_barrier();
    if (t + 2 < nt) STAGE((t + 2) % 3, t + 2);

    const char* bA = (const char*)lds + (size_t)(t % 3) * BUF * 2;
    const char* bB = bA + ASZ * 2;
    bf16x8 af[NFR], bq[4];
#pragma unroll
    for (int i = 0; i < NFR; ++i){
      const int ra = wr * (BM / 2) + i * 16 + lr;
      const int p = ra >> 1;
      const int slot = (((ra & 1) << 2) | lg) ^ (p & 7);
      af[i] = *(const bf16x8*)(bA + p * 128 + slot * 16);
    }
#pragma unroll
    for (int j = 0; j < 4; ++j){
      const int rb = wc * 64 + j * 16 + lr;
      const int p = rb >> 1;
      const int slot = (((rb & 1) << 2) | lg) ^ (p & 7);
      bq[j] = *(const bf16x8*)(bB + p * 128 + slot * 16);
    }
    __builtin_amdgcn_s_setprio(1);
#pragma unroll
    for (int i = 0; i < NFR; ++i)
#pragma unroll
      for (int j = 0; j < 4; ++j)
        acc[i][j] = __builtin_amdgcn_mfma_f32_16x16x32_bf16(af[i], bq[j], acc[i][j], 0, 0, 0);
    __builtin_amdgcn_s_setprio(0);
  }

#pragma unroll
  for (int i = 0; i < NFR; ++i){
#pragma unroll
    for (int r = 0; r < 4; ++r){
      const int row = m0 + wr * (BM / 2) + i * 16 + lg * 4 + r;
#pragma unroll
      for (int j = 0; j < 4; ++j){
        const int col = n0 + wc * 64 + j * 16 + lr;
        const float v = acc[i][j][r];
        if constexpr (MODE == M_RES){
          float* pp = outf + (size_t)row * N + col;
          *pp += v;
        } else if constexpr (MODE == M_GELU){
          float u = 0.7978845608028654f * (v + 0.044715f * v * v * v);
          u = fminf(fmaxf(u, -15.f), 15.f);
          const float ex = __expf(2.f * u);
          const float th = (ex - 1.f) / (ex + 1.f);
          outb[(size_t)row * N + col] = f2bf(0.5f * v * (1.f + th));
        }
      }
    }
  }
}

// ---------------- GEMM v6 (R6-verified): BM=BN=256, BK=64, 4-phase K-half pipeline ----------------
template<int MODE>
__global__ __launch_bounds__(512, 2) void gemm6_k(
    const u16* __restrict__ A, const u16* __restrict__ BT,
    int N, int K, int MB,
    u16* __restrict__ outb, float* __restrict__ outf, u16* __restrict__ vtout)
{
  __shared__ u16 lds[65536];

  const int tid  = threadIdx.x;
  const int wv   = tid >> 6, lane = tid & 63;
  const int wr   = wv >> 2,  wc   = wv & 3;
  const int lg   = lane >> 4, lr  = lane & 15;

  const int nwg = gridDim.x;
  const int bid = blockIdx.x;
  const int swz = ((nwg & 7) == 0) ? ((bid & 7) * (nwg >> 3) + (bid >> 3)) : bid;
  const int bm = swz % MB, bn = swz / MB;
  const int m0 = bm * 256, n0 = bn * 256;

  const int ll = lane >> 3;
  const int cc = lane & 7;
  const int lc = cc ^ ll;
  const int gr = (ll << 1) + (lc >> 2);
  const int gk = (lc & 3) << 3;

  const u16* gA = A  + (size_t)m0 * K + gk;
  const u16* gB = BT + (size_t)n0 * K + gk;

  f32x4 acc[8][4];
#pragma unroll
  for (int i = 0; i < 8; ++i)
#pragma unroll
    for (int j = 0; j < 4; ++j)
#pragma unroll
      for (int r = 0; r < 4; ++r) acc[i][j][r] = 0.f;

  const int nt = K >> 6;

  auto RB = [&](int tt, int kh, int bsel) -> char* {
    return (char*)lds + (((tt & 1) << 16) | (kh << 15) | (bsel << 14));
  };
  auto STG = [&](const u16* gsrc, int tt, int kh, int bsel){
    char* dst = RB(tt, kh, bsel);
    const size_t ko = (size_t)tt * 64 + kh * 32;
    gload16(gsrc + (size_t)((wv    ) * 16 + gr) * K + ko, dst + (wv    ) * 1024);
    gload16(gsrc + (size_t)((wv + 8) * 16 + gr) * K + ko, dst + (wv + 8) * 1024);
  };
  auto FRG = [&](int tt, int kh, int bsel, int row) -> bf16x8 {
    const int p = row >> 1;
    const int slot = (((row & 1) << 2) | lg) ^ (p & 7);
    return *(const bf16x8*)(RB(tt, kh, bsel) + p * 128 + slot * 16);
  };

  STG(gA, 0, 0, 0); STG(gB, 0, 0, 1);
  STG(gA, 0, 1, 0); STG(gB, 0, 1, 1);
  STG(gA, 1, 0, 0); STG(gB, 1, 0, 1);
  asm volatile("s_waitcnt vmcnt(4)" ::: "memory");
  __builtin_amdgcn_s_barrier();

  for (int u = 0; u < nt; ++u){
    bf16x8 bq[4], aa[4];
#pragma unroll
    for (int j = 0; j < 4; ++j) bq[j] = FRG(u, 0, 1, wc * 64 + j * 16 + lr);
#pragma unroll
    for (int i = 0; i < 4; ++i) aa[i] = FRG(u, 0, 0, wr * 128 + i * 16 + lr);
    if (u + 1 < nt) STG(gA, u + 1, 1, 0);
    __builtin_amdgcn_s_barrier();
    asm volatile("s_waitcnt lgkmcnt(0)" ::: "memory");
    __builtin_amdgcn_s_setprio(1);
#pragma unroll
    for (int i = 0; i < 4; ++i)
#pragma unroll
      for (int j = 0; j < 4; ++j)
        acc[i][j] = __builtin_amdgcn_mfma_f32_16x16x32_bf16(aa[i], bq[j], acc[i][j], 0, 0, 0);
    __builtin_amdgcn_s_setprio(0);
    __builtin_amdgcn_s_barrier();

    bf16x8 ab[4];
#pragma unroll
    for (int i = 0; i < 4; ++i) ab[i] = FRG(u, 0, 0, wr * 128 + (4 + i) * 16 + lr);
    if (u + 1 < nt) STG(gB, u + 1, 1, 1);
    __builtin_amdgcn_s_barrier();
    asm volatile("s_waitcnt lgkmcnt(0)" ::: "memory");
    __builtin_amdgcn_s_setprio(1);
#pragma unroll
    for (int i = 0; i < 4; ++i)
#pragma unroll
      for (int j = 0; j < 4; ++j)
        acc[4 + i][j] = __builtin_amdgcn_mfma_f32_16x16x32_bf16(ab[i], bq[j], acc[4 + i][j], 0, 0, 0);
    __builtin_amdgcn_s_setprio(0);
    __builtin_amdgcn_s_barrier();

    bf16x8 bq2[4], ac[4];
#pragma unroll
    for (int j = 0; j < 4; ++j) bq2[j] = FRG(u, 1, 1, wc * 64 + j * 16 + lr);
#pragma unroll
    for (int i = 0; i < 4; ++i) ac[i] = FRG(u, 1, 0, wr * 128 + i * 16 + lr);
    if (u + 2 < nt) STG(gA, u + 2, 0, 0);
    __builtin_amdgcn_s_barrier();
    asm volatile("s_waitcnt lgkmcnt(0)" ::: "memory");
    __builtin_amdgcn_s_setprio(1);
#pragma unroll
    for (int i = 0; i < 4; ++i)
#pragma unroll
      for (int j = 0; j < 4; ++j)
        acc[i][j] = __builtin_amdgcn_mfma_f32_16x16x32_bf16(ac[i], bq2[j], acc[i][j], 0, 0, 0);
    __builtin_amdgcn_s_setprio(0);
    __builtin_amdgcn_s_barrier();

    bf16x8 ad[4];
#pragma unroll
    for (int i = 0; i < 4; ++i) ad[i] = FRG(u, 1, 0, wr * 128 + (4 + i) * 16 + lr);
    if (u + 2 < nt) STG(gB, u + 2, 0, 1);
    if (u + 2 < nt)      asm volatile("s_waitcnt vmcnt(4)" ::: "memory");
    else if (u + 1 < nt) asm volatile("s_waitcnt vmcnt(0)" ::: "memory");
    __builtin_amdgcn_s_barrier();
    asm volatile("s_waitcnt lgkmcnt(0)" ::: "memory");
    __builtin_amdgcn_s_setprio(1);
#pragma unroll
    for (int i = 0; i < 4; ++i)
#pragma unroll
      for (int j = 0; j < 4; ++j)
        acc[4 + i][j] = __builtin_amdgcn_mfma_f32_16x16x32_bf16(ad[i], bq2[j], acc[4 + i][j], 0, 0, 0);
    __builtin_amdgcn_s_setprio(0);
    __builtin_amdgcn_s_barrier();
  }

#pragma unroll
  for (int i = 0; i < 8; ++i){
    if constexpr (MODE == M_QKV){
#pragma unroll
      for (int j = 0; j < 4; ++j){
        const int colb = n0 + wc * 64 + j * 16;
        if (colb < 4096){
#pragma unroll
          for (int r = 0; r < 4; ++r){
            const int row = m0 + wr * 128 + i * 16 + lg * 4 + r;
            outb[(size_t)row * 6144 + colb + lr] = f2bf(acc[i][j][r]);
          }
        } else {
          const int srow = m0 + wr * 128 + i * 16 + lg * 4;
          const int b = srow >> 10, s = srow & 1023;
          int dd = colb + lr - 4096;
          const int hh = dd >> 7; dd &= 127;
          ushort4 o;
          o.x = f2bf(acc[i][j][0]); o.y = f2bf(acc[i][j][1]);
          o.z = f2bf(acc[i][j][2]); o.w = f2bf(acc[i][j][3]);
          *(ushort4*)(vtout + ((size_t)(b * 16 + hh) * 128 + dd) * 1024 + s) = o;
        }
      }
    } else {
#pragma unroll
      for (int r = 0; r < 4; ++r){
        const int row = m0 + wr * 128 + i * 16 + lg * 4 + r;
#pragma unroll
        for (int j = 0; j < 4; ++j){
          const int col = n0 + wc * 64 + j * 16 + lr;
          const float v = acc[i][j][r];
          if constexpr (MODE == M_RES){
            float* pp = outf + (size_t)row * N + col;
            *pp += v;
          } else { // M_GELU
            float u2 = 0.7978845608028654f * (v + 0.044715f * v * v * v);
            u2 = fminf(fmaxf(u2, -15.f), 15.f);
            const float ex = __expf(2.f * u2);
            const float th = (ex - 1.f) / (ex + 1.f);
            outb[(size_t)row * N + col] = f2bf(0.5f * v * (1.f + th));
          }
        }
      }
    }
  }
}

// ---------------- GEMM v8 (R12-verified): fp8, BM=BN=256, BK=32, pre-swizzled sources,
// linear global_load_lds staging, conflict-free ds_read_b64, epilogues GELU/LSE ----------------
template<int MODE>
__global__ __launch_bounds__(512, 2) void gemm8_k(
    const u8* __restrict__ A8, const u8* __restrict__ B8,
    int N, int K, int MB,
    u16* __restrict__ outb,
    float* __restrict__ partial, float* __restrict__ tokl,
    const int* __restrict__ ids)
{
  __shared__ u8 lds8[2 * 16384];

  const int tid  = threadIdx.x;
  const int wv   = tid >> 6, lane = tid & 63;
  const int wr   = wv >> 2,  wc   = wv & 3;
  const int lg   = lane >> 4, lr  = lane & 15;

  const int nwg = gridDim.x;
  const int bid = blockIdx.x;
  const int swz = ((nwg & 7) == 0) ? ((bid & 7) * (nwg >> 3) + (bid >> 3)) : bid;
  const int bm = swz % MB, bn = swz / MB;
  const int m0 = bm * 256, n0 = bn * 256;

  const int sr = lane >> 1, sh = (lane & 1) << 4;
  const u8* gA = A8 + (size_t)(m0 + wv * 32 + sr) * K + sh;
  const u8* gB = B8 + (size_t)(n0 + wv * 32 + sr) * K + sh;

  f32x4 acc[8][4];
#pragma unroll
  for (int i = 0; i < 8; ++i)
#pragma unroll
    for (int j = 0; j < 4; ++j)
#pragma unroll
      for (int r = 0; r < 4; ++r) acc[i][j][r] = 0.f;

  const int nt = K >> 5;

  auto STAGE = [&](int bi, int kt){
    u8* base = lds8 + bi * 16384;
    gload16(gA + (size_t)kt * 32, base + wv * 1024);
    gload16(gB + (size_t)kt * 32, base + 8192 + wv * 1024);
  };

  auto FR8 = [&](const u8* base, int r) -> long {
    const int p = r >> 2;
    const int g = ((r & 3) << 2) | (lg ^ (p & 3));
    return *(const long*)(base + p * 128 + g * 8);
  };

  STAGE(0, 0);
  STAGE(1, 1);

  for (int t = 0; t < nt; ++t){
    if (t + 1 < nt) asm volatile("s_waitcnt vmcnt(2)" ::: "memory");
    else            asm volatile("s_waitcnt vmcnt(0)" ::: "memory");
    __builtin_amdgcn_s_barrier();

    const u8* bA = lds8 + (t & 1) * 16384;
    const u8* bB = bA + 8192;
    long af[8], bq[4];
#pragma unroll
    for (int i = 0; i < 8; ++i) af[i] = FR8(bA, wr * 128 + i * 16 + lr);
#pragma unroll
    for (int j = 0; j < 4; ++j) bq[j] = FR8(bB, wc * 64 + j * 16 + lr);
    asm volatile("s_waitcnt lgkmcnt(0)" ::: "memory");
    __builtin_amdgcn_s_barrier();

    if (t + 2 < nt) STAGE(t & 1, t + 2);

    __builtin_amdgcn_s_setprio(1);
#pragma unroll
    for (int i = 0; i < 8; ++i)
#pragma unroll
      for (int j = 0; j < 4; ++j)
        acc[i][j] = __builtin_amdgcn_mfma_f32_16x16x32_fp8_fp8(af[i], bq[j], acc[i][j], 0, 0, 0);
    __builtin_amdgcn_s_setprio(0);
  }

  // epilogues: weights were scaled x16, undo with 1/16
#pragma unroll
  for (int i = 0; i < 8; ++i){
    if constexpr (MODE == M_LSE){
#pragma unroll
      for (int r = 0; r < 4; ++r){
        const int row = m0 + wr * 128 + i * 16 + lg * 4 + r;
        const int id = ids[row];
        float esum = 0.f;
#pragma unroll
        for (int j = 0; j < 4; ++j){
          const int col = n0 + wc * 64 + j * 16 + lr;
          const float v = acc[i][j][r] * 0.0625f;
          if (col == id) tokl[row] = v;
          esum += __expf(v);
        }
#pragma unroll
        for (int off = 8; off >= 1; off >>= 1) esum += __shfl_xor(esum, off);
        if (lr == 0) partial[(size_t)row * 500 + bn * 4 + wc] = esum;
      }
    } else { // M_GELU
#pragma unroll
      for (int r = 0; r < 4; ++r){
        const int row = m0 + wr * 128 + i * 16 + lg * 4 + r;
#pragma unroll
        for (int j = 0; j < 4; ++j){
          const int col = n0 + wc * 64 + j * 16 + lr;
          const float v = acc[i][j][r] * 0.0625f;
          float u = 0.7978845608028654f * (v + 0.044715f * v * v * v);
          u = fminf(fmaxf(u, -15.f), 15.f);
          const float ex = __expf(2.f * u);
          const float th = (ex - 1.f) / (ex + 1.f);
          outb[(size_t)row * N + col] = f2bf(0.5f * v * (1.f + th));
        }
      }
    }
  }
}

// ---------------- flash attention (causal), 1 wave / 16 q-rows ----------------
// R18: XCD-locality decode (bh = bid&63 -> all q-tiles of a head on one XCD's L2)
// + setprio around MFMA clusters (T5, +4-7% measured on attn).
__global__ __launch_bounds__(64) void attn_k(const u16* __restrict__ qkv, const u16* __restrict__ vT, u16* __restrict__ o16)
{
  __shared__ u16 P[16 * 40];
  const int bid = blockIdx.x;
  const int bh = bid & 63, qt = bid >> 6;
  const int h = bh & 15, b = bh >> 4;
  const int lane = threadIdx.x, lg = lane >> 4, lr = lane & 15;
  const int q0 = qt << 4;
  const u16* qrow  = qkv + (size_t)(b * 1024 + q0 + lr) * 6144 + h * 128;
  const u16* krow  = qkv + (size_t)(b * 1024 + lr) * 6144 + 2048 + h * 128;
  const u16* vbase = vT + (size_t)(b * 16 + h) * 128 * 1024;

  bf16x8 qf[4];
#pragma unroll
  for (int c = 0; c < 4; ++c) qf[c] = *(const bf16x8*)(qrow + c * 32 + lg * 8);

  float m[4], l[4];
  f32x4 oacc[8];
#pragma unroll
  for (int r = 0; r < 4; ++r){ m[r] = -1e30f; l[r] = 0.f; }
#pragma unroll
  for (int f = 0; f < 8; ++f)
#pragma unroll
    for (int r = 0; r < 4; ++r) oacc[f][r] = 0.f;

  const float scale = 0.08838834764831845f;
  const int nk2 = (qt >> 1) + 1;
  for (int k2 = 0; k2 < nk2; ++k2){
    float e[2][4];
    float rmax[4];
#pragma unroll
    for (int r = 0; r < 4; ++r) rmax[r] = -1e30f;
#pragma unroll
    for (int hh = 0; hh < 2; ++hh){
      const int kt = k2 * 2 + hh;
      if (kt <= qt){
        f32x4 s;
#pragma unroll
        for (int r = 0; r < 4; ++r) s[r] = 0.f;
        __builtin_amdgcn_s_setprio(1);
#pragma unroll
        for (int c = 0; c < 4; ++c){
          bf16x8 kf = *(const bf16x8*)(krow + (size_t)(kt * 16) * 6144 + c * 32 + lg * 8);
          s = __builtin_amdgcn_mfma_f32_16x16x32_bf16(qf[c], kf, s, 0, 0, 0);
        }
        __builtin_amdgcn_s_setprio(0);
#pragma unroll
        for (int r = 0; r < 4; ++r){
          float sv = s[r] * scale;
          if (kt * 16 + lr > q0 + lg * 4 + r) sv = -1e30f;
          e[hh][r] = sv;
          rmax[r] = fmaxf(rmax[r], sv);
        }
      } else {
#pragma unroll
        for (int r = 0; r < 4; ++r) e[hh][r] = -1e30f;
      }
    }
#pragma unroll
    for (int off = 8; off >= 1; off >>= 1)
#pragma unroll
      for (int r = 0; r < 4; ++r) rmax[r] = fmaxf(rmax[r], __shfl_xor(rmax[r], off));
    float corr[4], rsum[4];
#pragma unroll
    for (int r = 0; r < 4; ++r){
      const float mn = fmaxf(m[r], rmax[r]);
      corr[r] = __expf(m[r] - mn);
      m[r] = mn;
      const float e0 = __expf(e[0][r] - mn);
      const float e1 = __expf(e[1][r] - mn);
      e[0][r] = e0; e[1][r] = e1;
      rsum[r] = e0 + e1;
    }
#pragma unroll
    for (int off = 8; off >= 1; off >>= 1)
#pragma unroll
      for (int r = 0; r < 4; ++r) rsum[r] += __shfl_xor(rsum[r], off);
#pragma unroll
    for (int r = 0; r < 4; ++r) l[r] = l[r] * corr[r] + rsum[r];
#pragma unroll
    for (int hh = 0; hh < 2; ++hh)
#pragma unroll
      for (int r = 0; r < 4; ++r)
        P[(lg * 4 + r) * 40 + hh * 16 + lr] = f2bf(e[hh][r]);
#pragma unroll
    for (int f = 0; f < 8; ++f)
#pragma unroll
      for (int r = 0; r < 4; ++r) oacc[f][r] = oacc[f][r] * corr[r];
    __syncthreads();
    const bf16x8 pa = *(const bf16x8*)((const u16*)P + lr * 40 + lg * 8);
    __builtin_amdgcn_s_setprio(1);
#pragma unroll
    for (int f = 0; f < 8; ++f){
      bf16x8 vb = *(const bf16x8*)(vbase + (size_t)(f * 16 + lr) * 1024 + k2 * 32 + lg * 8);
      oacc[f] = __builtin_amdgcn_mfma_f32_16x16x32_bf16(pa, vb, oacc[f], 0, 0, 0);
    }
    __builtin_amdgcn_s_setprio(0);
    __syncthreads();
  }
  u16* orow = o16 + (size_t)(b * 1024 + q0 + lg * 4) * 2048 + h * 128;
#pragma unroll
  for (int r = 0; r < 4; ++r){
    const float linv = 1.0f / l[r];
#pragma unroll
    for (int f = 0; f < 8; ++f)
      orow[(size_t)r * 2048 + f * 16 + lr] = f2bf(oacc[f][r] * linv);
  }
}

// ---------------- logsumexp finalize + surprisal ----------------
__global__ __launch_bounds__(256) void lse_k(const float* __restrict__ partial, const float* __restrict__ tokl,
                                             const int* __restrict__ amask, float* __restrict__ surp)
{
  const int row = blockIdx.x, t = threadIdx.x, lane = t & 63, wid = t >> 6;
  float s = 0.f;
  if (t < 250) s = partial[(size_t)row * 500 + t] + partial[(size_t)row * 500 + t + 250];
#pragma unroll
  for (int off = 32; off >= 1; off >>= 1) s += __shfl_down(s, off);
  __shared__ float rb[4];
  if (lane == 0) rb[wid] = s;
  __syncthreads();
  if (t == 0){
    const float tot = rb[0] + rb[1] + rb[2] + rb[3];
    surp[row] = (logf(tot) - tokl[row]) * 1.4426950408889634f * (float)amask[row];
  }
}

// ---------------- mean-pool over sequence ----------------
__global__ __launch_bounds__(256) void pool_k(const u16* __restrict__ h16, float* __restrict__ pooled)
{
  const int d = blockIdx.x * 256 + threadIdx.x;
  const int b = blockIdx.y;
  const u16* p = h16 + (size_t)b * 1024 * 2048 + d;
  float a0 = 0.f, a1 = 0.f, a2 = 0.f, a3 = 0.f;
  for (int s = 0; s < 1024; s += 4){
    a0 += bf2f(p[(size_t)(s + 0) * 2048]);
    a1 += bf2f(p[(size_t)(s + 1) * 2048]);
    a2 += bf2f(p[(size_t)(s + 2) * 2048]);
    a3 += bf2f(p[(size_t)(s + 3) * 2048]);
  }
  pooled[b * 2048 + d] = (a0 + a1 + a2 + a3) * (1.f / 1024.f);
}

// ---------------- classifier head ----------------
__global__ __launch_bounds__(256) void cls_k(const float* __restrict__ pooled, const float* __restrict__ surp,
                                             const int* __restrict__ amask, const float* __restrict__ sent,
                                             const float* __restrict__ ppl, const float* __restrict__ redw,
                                             const float* __restrict__ redb, const float* __restrict__ clsw,
                                             const float* __restrict__ clsb, float* __restrict__ out)
{
  const int b = blockIdx.x, t = threadIdx.x;
  const int lane = t & 63, wid = t >> 6;
  __shared__ float pl[2048];
  __shared__ float feats[112];
  __shared__ float rbuf[2][4];
#pragma unroll
  for (int i = 0; i < 8; ++i) pl[t + i * 256] = pooled[b * 2048 + t + i * 256];
  float ssum = 0.f, msum = 0.f;
#pragma unroll
  for (int i = 0; i < 4; ++i){
    const int s = t + i * 256;
    ssum += surp[b * 1024 + s];
    msum += (float)amask[b * 1024 + s];
  }
#pragma unroll
  for (int off = 32; off >= 1; off >>= 1){ ssum += __shfl_down(ssum, off); msum += __shfl_down(msum, off); }
  if (lane == 0){ rbuf[0][wid] = ssum; rbuf[1][wid] = msum; }
  __syncthreads();
  if (t == 0){
    float a = 0.f, c = 0.f;
    for (int i = 0; i < 4; ++i){ a += rbuf[0][i]; c += rbuf[1][i]; }
    feats[104] = a / c;
  }
  if (t >= 100 && t < 103) feats[t] = sent[b * 3 + (t - 100)];
  if (t == 103) feats[103] = ppl[b];
  if (t < 100){
    float a = redb[t];
    for (int d = 0; d < 2048; ++d) a += pl[d] * redw[d * 100 + t];
    feats[t] = (a > 0.f) ? a : 0.01f * a;
  }
  __syncthreads();
  if (t < 3){
    float a = clsb[t];
    for (int i = 0; i < 105; ++i) a += feats[i] * clsw[i * 3 + t];
    out[b * 3 + t] = a;
  }
}

// ---------------- host launch ----------------
extern "C" void kernel_launch(void* const* d_in, const int* in_sizes, int n_in,
                              void* d_out, int out_size, void* d_ws, size_t ws_size,
                              hipStream_t stream)
{
  (void)in_sizes; (void)n_in; (void)out_size; (void)ws_size;
  const int*   ids   = (const int*)d_in[0];
  const int*   amask = (const int*)d_in[1];
  const float* sent  = (const float*)d_in[2];
  const float* ppl   = (const float*)d_in[3];
  const float* emb   = (const float*)d_in[4];
  const float* ln1g  = (const float*)d_in[5];
  const float* ln1b  = (const float*)d_in[6];
  const float* qkvw  = (const float*)d_in[7];
  const float* wow   = (const float*)d_in[8];
  const float* ln2g  = (const float*)d_in[9];
  const float* ln2b  = (const float*)d_in[10];
  const float* w1    = (const float*)d_in[11];
  const float* w2    = (const float*)d_in[12];
  const float* lnfg  = (const float*)d_in[13];
  const float* lnfb  = (const float*)d_in[14];
  const float* headw = (const float*)d_in[15];
  const float* redw  = (const float*)d_in[16];
  const float* redb  = (const float*)d_in[17];
  const float* clsw  = (const float*)d_in[18];
  const float* clsb  = (const float*)d_in[19];
  float* out = (float*)d_out;

  char* p = (char*)d_ws;
  u16* wqkvT = (u16*)p; p += (size_t)2 * 6144 * 2048 * 2;
  u16* woT   = (u16*)p; p += (size_t)2 * 2048 * 2048 * 2;
  u8*  w18   = (u8*)p;  p += (size_t)2 * 8192 * 2048;
  u16* w2T   = (u16*)p; p += (size_t)2 * 2048 * 8192 * 2;
  u8*  wh8   = (u8*)p;  p += (size_t)32000 * 2048;
  float* xbuf = (float*)p; p += (size_t)4096 * 2048 * 4;
  u16* h16   = (u16*)p; p += (size_t)4096 * 2048 * 2;
  u8*  h8    = (u8*)p;  p += (size_t)4096 * 2048;
  u16* qkv16 = (u16*)p;
  u16* vT16  = (u16*)(p + (size_t)4096 * 6144 * 2);
  u16* ffn16 = (u16*)p;
  p += (size_t)4096 * 6144 * 2 + (size_t)4096 * 2048 * 2;
  u16* o16   = (u16*)p; p += (size_t)4096 * 2048 * 2;
  float* partial = (float*)p; p += (size_t)4096 * 500 * 4;
  float* tokl = (float*)p; p += (size_t)4096 * 4;
  float* surp = (float*)p; p += (size_t)4096 * 4;
  float* pooled = (float*)p; p += (size_t)4 * 2048 * 4;

  for (int l = 0; l < 2; ++l){
    transp_k<<<dim3(6144/64, 2048/64), 256, 0, stream>>>(qkvw + (size_t)l*2048*6144, wqkvT + (size_t)l*6144*2048, 2048, 6144);
    transp_k<<<dim3(2048/64, 2048/64), 256, 0, stream>>>(wow  + (size_t)l*2048*2048, woT   + (size_t)l*2048*2048, 2048, 2048);
    transp8_k<<<dim3(8192/64, 2048/64), 256, 0, stream>>>(w1   + (size_t)l*2048*8192, w18   + (size_t)l*8192*2048, 2048, 8192);
    transp_k<<<dim3(2048/64, 8192/64), 256, 0, stream>>>(w2   + (size_t)l*8192*2048, w2T   + (size_t)l*2048*8192, 8192, 2048);
  }
  transp8_k<<<dim3(32000/64, 2048/64), 256, 0, stream>>>(headw, wh8, 2048, 32000);

  embed_k<<<dim3(4096, 8), 256, 0, stream>>>(ids, emb, xbuf);

  for (int l = 0; l < 2; ++l){
    ln_k<0><<<4096, 256, 0, stream>>>(xbuf, ln1g + l*2048, ln1b + l*2048, h16, nullptr);
    gemm6_k<M_QKV><<<16*24, 512, 0, stream>>>(h16, wqkvT + (size_t)l*6144*2048, 6144, 2048, 16,
                                              qkv16, nullptr, vT16);
    attn_k<<<4096, 64, 0, stream>>>(qkv16, vT16, o16);
    gemm2_k<M_RES,128><<<32*8, 512, 0, stream>>>(o16, woT + (size_t)l*2048*2048, 2048, 2048, 32,
                                                 nullptr, xbuf);
    ln_k<1><<<4096, 256, 0, stream>>>(xbuf, ln2g + l*2048, ln2b + l*2048, nullptr, h8);
    gemm8_k<M_GELU><<<16*32, 512, 0, stream>>>(h8, w18 + (size_t)l*8192*2048, 8192, 2048, 16,
                                               ffn16, nullptr, nullptr, nullptr);
    gemm2_k<M_RES,128><<<32*8, 512, 0, stream>>>(ffn16, w2T + (size_t)l*2048*8192, 2048, 8192, 32,
                                                 nullptr, xbuf);
  }
  ln_k<2><<<4096, 256, 0, stream>>>(xbuf, lnfg, lnfb, h16, h8);
  gemm8_k<M_LSE><<<16*125, 512, 0, stream>>>(h8, wh8, 32000, 2048, 16,
                                             nullptr, partial, tokl, ids);
  lse_k<<<4096, 256, 0, stream>>>(partial, tokl, amask, surp);
  pool_k<<<dim3(8, 4), 256, 0, stream>>>(h16, pooled);
  cls_k<<<4, 256, 0, stream>>>(pooled, surp, amask, sent, ppl, redw, redb, clsw, clsb, out);
}

// Round 20
// 2138.329 us; speedup vs baseline: 1.0919x; 1.0006x over previous
//
#include <hip/hip_runtime.h>

typedef unsigned short u16;
typedef unsigned char u8;
typedef __bf16 bf16x8 __attribute__((ext_vector_type(8)));
typedef float f32x4 __attribute__((ext_vector_type(4)));

__device__ __forceinline__ u16 f2bf(float f){
  unsigned u = __float_as_uint(f);
  unsigned r = u + 0x7FFFu + ((u >> 16) & 1u);
  return (u16)(r >> 16);
}
__device__ __forceinline__ float bf2f(u16 v){ return __uint_as_float(((unsigned)v) << 16); }

// f32 -> OCP e4m3fn, RNE, saturating (verified on-device R8-R18)
__device__ __forceinline__ u8 f2fp8(float f){
  unsigned u = __float_as_uint(f);
  u8 s = (u >> 24) & 0x80;
  float a = __uint_as_float(u & 0x7FFFFFFF);
  if (!(a < 464.f)) return s | 0x7E;
  unsigned eu = u & 0x7F800000u;
  unsigned cb = eu + (20u << 23);
  const unsigned cmin = 141u << 23;
  float c = __uint_as_float(cb > cmin ? cb : cmin);
  float q = (a + c) - c;
  if (q > 448.f) return s | 0x7E;
  if (q == 0.f) return s;
  unsigned uq = __float_as_uint(q);
  int eq = (int)(uq >> 23) - 127;
  if (eq < -6){
    int mq = (int)(q * 512.f);
    return s | (u8)mq;
  }
  return s | (u8)(((eq + 7) << 3) | ((uq >> 20) & 7));
}

__device__ __forceinline__ void gload16(const void* g, void* l){
  __builtin_amdgcn_global_load_lds(
      (const __attribute__((address_space(1))) unsigned int*)g,
      (__attribute__((address_space(3))) unsigned int*)l, 16, 0, 0);
}

// ---------------- weight transpose+convert: in f32 [K][N] -> out bf16 [N][K] ----------------
__global__ __launch_bounds__(256) void transp_k(const float* __restrict__ in, u16* __restrict__ out, int K, int N)
{
  __shared__ float tl[64][65];
  const int n0 = blockIdx.x * 64, k0 = blockIdx.y * 64;
  const int t = threadIdx.x;
  const int r = t >> 4, c4 = t & 15;
#pragma unroll
  for (int i = 0; i < 4; ++i){
    float4 v = *(const float4*)(in + (size_t)(k0 + r + i*16) * N + n0 + c4*4);
    tl[r + i*16][c4*4 + 0] = v.x; tl[r + i*16][c4*4 + 1] = v.y;
    tl[r + i*16][c4*4 + 2] = v.z; tl[r + i*16][c4*4 + 3] = v.w;
  }
  __syncthreads();
#pragma unroll
  for (int i = 0; i < 4; ++i){
    const int n = r + i*16;
    ushort4 o;
    o.x = f2bf(tl[c4*4 + 0][n]); o.y = f2bf(tl[c4*4 + 1][n]);
    o.z = f2bf(tl[c4*4 + 2][n]); o.w = f2bf(tl[c4*4 + 3][n]);
    *(ushort4*)(out + (size_t)(n0 + n) * K + k0 + c4*4) = o;
  }
}

// ---------------- weight transpose+convert: f32 [K][N] -> fp8 [N][K], scaled x16,
// PRE-SWIZZLED: (row,k) -> row*K + (k&~31) + (((k>>3)&3)^((row>>2)&3))*8 + (k&7)
__global__ __launch_bounds__(256) void transp8_k(const float* __restrict__ in, u8* __restrict__ out, int K, int N)
{
  __shared__ float tl[64][65];
  const int n0 = blockIdx.x * 64, k0 = blockIdx.y * 64;
  const int t = threadIdx.x;
  const int r = t >> 4, c4 = t & 15;
#pragma unroll
  for (int i = 0; i < 4; ++i){
    float4 v = *(const float4*)(in + (size_t)(k0 + r + i*16) * N + n0 + c4*4);
    tl[r + i*16][c4*4 + 0] = v.x; tl[r + i*16][c4*4 + 1] = v.y;
    tl[r + i*16][c4*4 + 2] = v.z; tl[r + i*16][c4*4 + 3] = v.w;
  }
  __syncthreads();
#pragma unroll
  for (int i = 0; i < 4; ++i){
    const int n = r + i*16;
    uchar4 o;
    o.x = f2fp8(tl[c4*4 + 0][n] * 16.f); o.y = f2fp8(tl[c4*4 + 1][n] * 16.f);
    o.z = f2fp8(tl[c4*4 + 2][n] * 16.f); o.w = f2fp8(tl[c4*4 + 3][n] * 16.f);
    const int ng = n0 + n;
    const int k = k0 + c4 * 4;
    const int key = (ng >> 2) & 3;
    const size_t addr = (size_t)ng * K + (k & ~31) + ((((k >> 3) & 3) ^ key) << 3) + (k & 7);
    *(uchar4*)(out + addr) = o;
  }
}

// ---------------- embedding gather ----------------
__global__ __launch_bounds__(256) void embed_k(const int* __restrict__ ids, const float* __restrict__ emb, float* __restrict__ x)
{
  const int row = blockIdx.x;
  const int c = blockIdx.y * 256 + threadIdx.x;
  x[(size_t)row * 2048 + c] = emb[(size_t)ids[row] * 2048 + c];
}

// ---------------- LayerNorm f32 -> {bf16, pre-swizzled fp8} OM: 0=bf16, 1=fp8, 2=both ----------------
template<int OM>
__global__ __launch_bounds__(256) void ln_k(const float* __restrict__ x, const float* __restrict__ gw,
                                            const float* __restrict__ bw, u16* __restrict__ o, u8* __restrict__ o8)
{
  const int row = blockIdx.x, t = threadIdx.x;
  const int lane = t & 63, wid = t >> 6;
  const float4* xr = (const float4*)(x + (size_t)row * 2048);
  float4 v1 = xr[t], v2 = xr[t + 256];
  float s1 = v1.x + v1.y + v1.z + v1.w + v2.x + v2.y + v2.z + v2.w;
  float s2 = v1.x*v1.x + v1.y*v1.y + v1.z*v1.z + v1.w*v1.w
           + v2.x*v2.x + v2.y*v2.y + v2.z*v2.z + v2.w*v2.w;
#pragma unroll
  for (int off = 32; off >= 1; off >>= 1){ s1 += __shfl_down(s1, off); s2 += __shfl_down(s2, off); }
  __shared__ float rb[2][4];
  __shared__ float mv[2];
  if (lane == 0){ rb[0][wid] = s1; rb[1][wid] = s2; }
  __syncthreads();
  if (t == 0){
    float a = rb[0][0] + rb[0][1] + rb[0][2] + rb[0][3];
    float q = rb[1][0] + rb[1][1] + rb[1][2] + rb[1][3];
    float mean = a * (1.f/2048.f);
    float var  = q * (1.f/2048.f) - mean*mean;
    mv[0] = mean; mv[1] = rsqrtf(var + 1e-5f);
  }
  __syncthreads();
  const float mean = mv[0], rstd = mv[1];
  const float4* g4 = (const float4*)gw;
  const float4* b4 = (const float4*)bw;
  float4 ga = g4[t], ba = b4[t], gb = g4[t + 256], bb2 = b4[t + 256];
  float n1x = (v1.x - mean)*rstd*ga.x + ba.x;
  float n1y = (v1.y - mean)*rstd*ga.y + ba.y;
  float n1z = (v1.z - mean)*rstd*ga.z + ba.z;
  float n1w = (v1.w - mean)*rstd*ga.w + ba.w;
  float n2x = (v2.x - mean)*rstd*gb.x + bb2.x;
  float n2y = (v2.y - mean)*rstd*gb.y + bb2.y;
  float n2z = (v2.z - mean)*rstd*gb.z + bb2.z;
  float n2w = (v2.w - mean)*rstd*gb.w + bb2.w;
  if constexpr (OM != 1){
    ushort4 o1, o2;
    o1.x = f2bf(n1x); o1.y = f2bf(n1y); o1.z = f2bf(n1z); o1.w = f2bf(n1w);
    o2.x = f2bf(n2x); o2.y = f2bf(n2y); o2.z = f2bf(n2z); o2.w = f2bf(n2w);
    ((ushort4*)(o + (size_t)row * 2048))[t] = o1;
    ((ushort4*)(o + (size_t)row * 2048))[t + 256] = o2;
  }
  if constexpr (OM != 0){
    uchar4 q1, q2;
    q1.x = f2fp8(n1x); q1.y = f2fp8(n1y); q1.z = f2fp8(n1z); q1.w = f2fp8(n1w);
    q2.x = f2fp8(n2x); q2.y = f2fp8(n2y); q2.z = f2fp8(n2z); q2.w = f2fp8(n2w);
    const int key = (row >> 2) & 3;
    const int k1 = t * 4;
    const int k2 = 1024 + t * 4;
    const int a1 = (k1 & ~31) + ((((k1 >> 3) & 3) ^ key) << 3) + (k1 & 7);
    const int a2 = (k2 & ~31) + ((((k2 >> 3) & 3) ^ key) << 3) + (k2 & 7);
    *(uchar4*)(o8 + (size_t)row * 2048 + a1) = q1;
    *(uchar4*)(o8 + (size_t)row * 2048 + a2) = q2;
  }
}

enum { M_QKV = 0, M_RES = 1, M_GELU = 2, M_LSE = 3 };

// ---------------- GEMM v2 (R2-verified): BM=128, BK=32, triple-buffer, 1 barrier/tile ----------------
template<int MODE, int BM>
__global__ __launch_bounds__(512, 2) void gemm2_k(
    const u16* __restrict__ A, const u16* __restrict__ BT,
    int N, int K, int MB,
    u16* __restrict__ outb, float* __restrict__ outf)
{
  constexpr int BK  = 32;
  constexpr int ASZ = BM * BK;
  constexpr int BSZ = 256 * BK;
  constexpr int BUF = ASZ + BSZ;
  constexpr int NFR = BM / 32;
  __shared__ u16 lds[3 * BUF];

  const int tid  = threadIdx.x;
  const int wv   = tid >> 6, lane = tid & 63;
  const int wr   = wv >> 2,  wc   = wv & 3;
  const int lg   = lane >> 4, lr  = lane & 15;

  const int nwg = gridDim.x;
  const int bid = blockIdx.x;
  const int swz = ((nwg & 7) == 0) ? ((bid & 7) * (nwg >> 3) + (bid >> 3)) : bid;
  const int bm = swz % MB, bn = swz / MB;
  const int m0 = bm * BM, n0 = bn * 256;

  const int ll = lane >> 3;
  const int cc = lane & 7;
  const int lc = cc ^ ll;
  const int gr = (ll << 1) + (lc >> 2);
  const int gk = (lc & 3) << 3;

  const u16* gA = A  + (size_t)m0 * K + gk;
  const u16* gB = BT + (size_t)n0 * K + gk;

  f32x4 acc[NFR][4];
#pragma unroll
  for (int i = 0; i < NFR; ++i)
#pragma unroll
    for (int j = 0; j < 4; ++j)
#pragma unroll
      for (int r = 0; r < 4; ++r) acc[i][j][r] = 0.f;

  const int nt = K >> 5;

  auto STAGE = [&](int bi, int kt){
    char* bA = (char*)lds + (size_t)bi * BUF * 2;
    char* bB = bA + ASZ * 2;
    const size_t ko = (size_t)kt * 32;
    gload16(gA + (size_t)(wv * 16 + gr) * K + ko, bA + wv * 1024);
    gload16(gB + (size_t)((wv    ) * 16 + gr) * K + ko, bB + (wv    ) * 1024);
    gload16(gB + (size_t)((wv + 8) * 16 + gr) * K + ko, bB + (wv + 8) * 1024);
  };

  STAGE(0, 0);
  STAGE(1, 1);

  for (int t = 0; t < nt; ++t){
    if (t + 1 < nt) asm volatile("s_waitcnt vmcnt(3) lgkmcnt(0)" ::: "memory");
    else            asm volatile("s_waitcnt vmcnt(0) lgkmcnt(0)" ::: "memory");
    __builtin_amdgcn_s_barrier();
    if (t + 2 < nt) STAGE((t + 2) % 3, t + 2);

    const char* bA = (const char*)lds + (size_t)(t % 3) * BUF * 2;
    const char* bB = bA + ASZ * 2;
    bf16x8 af[NFR], bq[4];
#pragma unroll
    for (int i = 0; i < NFR; ++i){
      const int ra = wr * (BM / 2) + i * 16 + lr;
      const int p = ra >> 1;
      const int slot = (((ra & 1) << 2) | lg) ^ (p & 7);
      af[i] = *(const bf16x8*)(bA + p * 128 + slot * 16);
    }
#pragma unroll
    for (int j = 0; j < 4; ++j){
      const int rb = wc * 64 + j * 16 + lr;
      const int p = rb >> 1;
      const int slot = (((rb & 1) << 2) | lg) ^ (p & 7);
      bq[j] = *(const bf16x8*)(bB + p * 128 + slot * 16);
    }
    __builtin_amdgcn_s_setprio(1);
#pragma unroll
    for (int i = 0; i < NFR; ++i)
#pragma unroll
      for (int j = 0; j < 4; ++j)
        acc[i][j] = __builtin_amdgcn_mfma_f32_16x16x32_bf16(af[i], bq[j], acc[i][j], 0, 0, 0);
    __builtin_amdgcn_s_setprio(0);
  }

#pragma unroll
  for (int i = 0; i < NFR; ++i){
#pragma unroll
    for (int r = 0; r < 4; ++r){
      const int row = m0 + wr * (BM / 2) + i * 16 + lg * 4 + r;
#pragma unroll
      for (int j = 0; j < 4; ++j){
        const int col = n0 + wc * 64 + j * 16 + lr;
        const float v = acc[i][j][r];
        if constexpr (MODE == M_RES){
          float* pp = outf + (size_t)row * N + col;
          *pp += v;
        } else if constexpr (MODE == M_GELU){
          float u = 0.7978845608028654f * (v + 0.044715f * v * v * v);
          u = fminf(fmaxf(u, -15.f), 15.f);
          const float ex = __expf(2.f * u);
          const float th = (ex - 1.f) / (ex + 1.f);
          outb[(size_t)row * N + col] = f2bf(0.5f * v * (1.f + th));
        }
      }
    }
  }
}

// ---------------- GEMM v6 (R6-verified): BM=BN=256, BK=64, 4-phase K-half pipeline ----------------
template<int MODE>
__global__ __launch_bounds__(512, 2) void gemm6_k(
    const u16* __restrict__ A, const u16* __restrict__ BT,
    int N, int K, int MB,
    u16* __restrict__ outb, float* __restrict__ outf, u16* __restrict__ vtout)
{
  __shared__ u16 lds[65536];

  const int tid  = threadIdx.x;
  const int wv   = tid >> 6, lane = tid & 63;
  const int wr   = wv >> 2,  wc   = wv & 3;
  const int lg   = lane >> 4, lr  = lane & 15;

  const int nwg = gridDim.x;
  const int bid = blockIdx.x;
  const int swz = ((nwg & 7) == 0) ? ((bid & 7) * (nwg >> 3) + (bid >> 3)) : bid;
  const int bm = swz % MB, bn = swz / MB;
  const int m0 = bm * 256, n0 = bn * 256;

  const int ll = lane >> 3;
  const int cc = lane & 7;
  const int lc = cc ^ ll;
  const int gr = (ll << 1) + (lc >> 2);
  const int gk = (lc & 3) << 3;

  const u16* gA = A  + (size_t)m0 * K + gk;
  const u16* gB = BT + (size_t)n0 * K + gk;

  f32x4 acc[8][4];
#pragma unroll
  for (int i = 0; i < 8; ++i)
#pragma unroll
    for (int j = 0; j < 4; ++j)
#pragma unroll
      for (int r = 0; r < 4; ++r) acc[i][j][r] = 0.f;

  const int nt = K >> 6;

  auto RB = [&](int tt, int kh, int bsel) -> char* {
    return (char*)lds + (((tt & 1) << 16) | (kh << 15) | (bsel << 14));
  };
  auto STG = [&](const u16* gsrc, int tt, int kh, int bsel){
    char* dst = RB(tt, kh, bsel);
    const size_t ko = (size_t)tt * 64 + kh * 32;
    gload16(gsrc + (size_t)((wv    ) * 16 + gr) * K + ko, dst + (wv    ) * 1024);
    gload16(gsrc + (size_t)((wv + 8) * 16 + gr) * K + ko, dst + (wv + 8) * 1024);
  };
  auto FRG = [&](int tt, int kh, int bsel, int row) -> bf16x8 {
    const int p = row >> 1;
    const int slot = (((row & 1) << 2) | lg) ^ (p & 7);
    return *(const bf16x8*)(RB(tt, kh, bsel) + p * 128 + slot * 16);
  };

  STG(gA, 0, 0, 0); STG(gB, 0, 0, 1);
  STG(gA, 0, 1, 0); STG(gB, 0, 1, 1);
  STG(gA, 1, 0, 0); STG(gB, 1, 0, 1);
  asm volatile("s_waitcnt vmcnt(4)" ::: "memory");
  __builtin_amdgcn_s_barrier();

  for (int u = 0; u < nt; ++u){
    bf16x8 bq[4], aa[4];
#pragma unroll
    for (int j = 0; j < 4; ++j) bq[j] = FRG(u, 0, 1, wc * 64 + j * 16 + lr);
#pragma unroll
    for (int i = 0; i < 4; ++i) aa[i] = FRG(u, 0, 0, wr * 128 + i * 16 + lr);
    if (u + 1 < nt) STG(gA, u + 1, 1, 0);
    __builtin_amdgcn_s_barrier();
    asm volatile("s_waitcnt lgkmcnt(0)" ::: "memory");
    __builtin_amdgcn_s_setprio(1);
#pragma unroll
    for (int i = 0; i < 4; ++i)
#pragma unroll
      for (int j = 0; j < 4; ++j)
        acc[i][j] = __builtin_amdgcn_mfma_f32_16x16x32_bf16(aa[i], bq[j], acc[i][j], 0, 0, 0);
    __builtin_amdgcn_s_setprio(0);
    __builtin_amdgcn_s_barrier();

    bf16x8 ab[4];
#pragma unroll
    for (int i = 0; i < 4; ++i) ab[i] = FRG(u, 0, 0, wr * 128 + (4 + i) * 16 + lr);
    if (u + 1 < nt) STG(gB, u + 1, 1, 1);
    __builtin_amdgcn_s_barrier();
    asm volatile("s_waitcnt lgkmcnt(0)" ::: "memory");
    __builtin_amdgcn_s_setprio(1);
#pragma unroll
    for (int i = 0; i < 4; ++i)
#pragma unroll
      for (int j = 0; j < 4; ++j)
        acc[4 + i][j] = __builtin_amdgcn_mfma_f32_16x16x32_bf16(ab[i], bq[j], acc[4 + i][j], 0, 0, 0);
    __builtin_amdgcn_s_setprio(0);
    __builtin_amdgcn_s_barrier();

    bf16x8 bq2[4], ac[4];
#pragma unroll
    for (int j = 0; j < 4; ++j) bq2[j] = FRG(u, 1, 1, wc * 64 + j * 16 + lr);
#pragma unroll
    for (int i = 0; i < 4; ++i) ac[i] = FRG(u, 1, 0, wr * 128 + i * 16 + lr);
    if (u + 2 < nt) STG(gA, u + 2, 0, 0);
    __builtin_amdgcn_s_barrier();
    asm volatile("s_waitcnt lgkmcnt(0)" ::: "memory");
    __builtin_amdgcn_s_setprio(1);
#pragma unroll
    for (int i = 0; i < 4; ++i)
#pragma unroll
      for (int j = 0; j < 4; ++j)
        acc[i][j] = __builtin_amdgcn_mfma_f32_16x16x32_bf16(ac[i], bq2[j], acc[i][j], 0, 0, 0);
    __builtin_amdgcn_s_setprio(0);
    __builtin_amdgcn_s_barrier();

    bf16x8 ad[4];
#pragma unroll
    for (int i = 0; i < 4; ++i) ad[i] = FRG(u, 1, 0, wr * 128 + (4 + i) * 16 + lr);
    if (u + 2 < nt) STG(gB, u + 2, 0, 1);
    if (u + 2 < nt)      asm volatile("s_waitcnt vmcnt(4)" ::: "memory");
    else if (u + 1 < nt) asm volatile("s_waitcnt vmcnt(0)" ::: "memory");
    __builtin_amdgcn_s_barrier();
    asm volatile("s_waitcnt lgkmcnt(0)" ::: "memory");
    __builtin_amdgcn_s_setprio(1);
#pragma unroll
    for (int i = 0; i < 4; ++i)
#pragma unroll
      for (int j = 0; j < 4; ++j)
        acc[4 + i][j] = __builtin_amdgcn_mfma_f32_16x16x32_bf16(ad[i], bq2[j], acc[4 + i][j], 0, 0, 0);
    __builtin_amdgcn_s_setprio(0);
    __builtin_amdgcn_s_barrier();
  }

#pragma unroll
  for (int i = 0; i < 8; ++i){
    if constexpr (MODE == M_QKV){
#pragma unroll
      for (int j = 0; j < 4; ++j){
        const int colb = n0 + wc * 64 + j * 16;
        if (colb < 4096){
#pragma unroll
          for (int r = 0; r < 4; ++r){
            const int row = m0 + wr * 128 + i * 16 + lg * 4 + r;
            outb[(size_t)row * 6144 + colb + lr] = f2bf(acc[i][j][r]);
          }
        } else {
          const int srow = m0 + wr * 128 + i * 16 + lg * 4;
          const int b = srow >> 10, s = srow & 1023;
          int dd = colb + lr - 4096;
          const int hh = dd >> 7; dd &= 127;
          ushort4 o;
          o.x = f2bf(acc[i][j][0]); o.y = f2bf(acc[i][j][1]);
          o.z = f2bf(acc[i][j][2]); o.w = f2bf(acc[i][j][3]);
          *(ushort4*)(vtout + ((size_t)(b * 16 + hh) * 128 + dd) * 1024 + s) = o;
        }
      }
    } else {
#pragma unroll
      for (int r = 0; r < 4; ++r){
        const int row = m0 + wr * 128 + i * 16 + lg * 4 + r;
#pragma unroll
        for (int j = 0; j < 4; ++j){
          const int col = n0 + wc * 64 + j * 16 + lr;
          const float v = acc[i][j][r];
          if constexpr (MODE == M_RES){
            float* pp = outf + (size_t)row * N + col;
            *pp += v;
          } else { // M_GELU
            float u2 = 0.7978845608028654f * (v + 0.044715f * v * v * v);
            u2 = fminf(fmaxf(u2, -15.f), 15.f);
            const float ex = __expf(2.f * u2);
            const float th = (ex - 1.f) / (ex + 1.f);
            outb[(size_t)row * N + col] = f2bf(0.5f * v * (1.f + th));
          }
        }
      }
    }
  }
}

// ---------------- GEMM v8 (R12-verified): fp8, BM=BN=256, BK=32, pre-swizzled sources,
// linear global_load_lds staging, conflict-free ds_read_b64, epilogues GELU/LSE ----------------
template<int MODE>
__global__ __launch_bounds__(512, 2) void gemm8_k(
    const u8* __restrict__ A8, const u8* __restrict__ B8,
    int N, int K, int MB,
    u16* __restrict__ outb,
    float* __restrict__ partial, float* __restrict__ tokl,
    const int* __restrict__ ids)
{
  __shared__ u8 lds8[2 * 16384];

  const int tid  = threadIdx.x;
  const int wv   = tid >> 6, lane = tid & 63;
  const int wr   = wv >> 2,  wc   = wv & 3;
  const int lg   = lane >> 4, lr  = lane & 15;

  const int nwg = gridDim.x;
  const int bid = blockIdx.x;
  const int swz = ((nwg & 7) == 0) ? ((bid & 7) * (nwg >> 3) + (bid >> 3)) : bid;
  const int bm = swz % MB, bn = swz / MB;
  const int m0 = bm * 256, n0 = bn * 256;

  const int sr = lane >> 1, sh = (lane & 1) << 4;
  const u8* gA = A8 + (size_t)(m0 + wv * 32 + sr) * K + sh;
  const u8* gB = B8 + (size_t)(n0 + wv * 32 + sr) * K + sh;

  f32x4 acc[8][4];
#pragma unroll
  for (int i = 0; i < 8; ++i)
#pragma unroll
    for (int j = 0; j < 4; ++j)
#pragma unroll
      for (int r = 0; r < 4; ++r) acc[i][j][r] = 0.f;

  const int nt = K >> 5;

  auto STAGE = [&](int bi, int kt){
    u8* base = lds8 + bi * 16384;
    gload16(gA + (size_t)kt * 32, base + wv * 1024);
    gload16(gB + (size_t)kt * 32, base + 8192 + wv * 1024);
  };

  auto FR8 = [&](const u8* base, int r) -> long {
    const int p = r >> 2;
    const int g = ((r & 3) << 2) | (lg ^ (p & 3));
    return *(const long*)(base + p * 128 + g * 8);
  };

  STAGE(0, 0);
  STAGE(1, 1);

  for (int t = 0; t < nt; ++t){
    if (t + 1 < nt) asm volatile("s_waitcnt vmcnt(2)" ::: "memory");
    else            asm volatile("s_waitcnt vmcnt(0)" ::: "memory");
    __builtin_amdgcn_s_barrier();

    const u8* bA = lds8 + (t & 1) * 16384;
    const u8* bB = bA + 8192;
    long af[8], bq[4];
#pragma unroll
    for (int i = 0; i < 8; ++i) af[i] = FR8(bA, wr * 128 + i * 16 + lr);
#pragma unroll
    for (int j = 0; j < 4; ++j) bq[j] = FR8(bB, wc * 64 + j * 16 + lr);
    asm volatile("s_waitcnt lgkmcnt(0)" ::: "memory");
    __builtin_amdgcn_s_barrier();

    if (t + 2 < nt) STAGE(t & 1, t + 2);

    __builtin_amdgcn_s_setprio(1);
#pragma unroll
    for (int i = 0; i < 8; ++i)
#pragma unroll
      for (int j = 0; j < 4; ++j)
        acc[i][j] = __builtin_amdgcn_mfma_f32_16x16x32_fp8_fp8(af[i], bq[j], acc[i][j], 0, 0, 0);
    __builtin_amdgcn_s_setprio(0);
  }

  // epilogues: weights were scaled x16, undo with 1/16
#pragma unroll
  for (int i = 0; i < 8; ++i){
    if constexpr (MODE == M_LSE){
#pragma unroll
      for (int r = 0; r < 4; ++r){
        const int row = m0 + wr * 128 + i * 16 + lg * 4 + r;
        const int id = ids[row];
        float esum = 0.f;
#pragma unroll
        for (int j = 0; j < 4; ++j){
          const int col = n0 + wc * 64 + j * 16 + lr;
          const float v = acc[i][j][r] * 0.0625f;
          if (col == id) tokl[row] = v;
          esum += __expf(v);
        }
#pragma unroll
        for (int off = 8; off >= 1; off >>= 1) esum += __shfl_xor(esum, off);
        if (lr == 0) partial[(size_t)row * 500 + bn * 4 + wc] = esum;
      }
    } else { // M_GELU
#pragma unroll
      for (int r = 0; r < 4; ++r){
        const int row = m0 + wr * 128 + i * 16 + lg * 4 + r;
#pragma unroll
        for (int j = 0; j < 4; ++j){
          const int col = n0 + wc * 64 + j * 16 + lr;
          const float v = acc[i][j][r] * 0.0625f;
          float u = 0.7978845608028654f * (v + 0.044715f * v * v * v);
          u = fminf(fmaxf(u, -15.f), 15.f);
          const float ex = __expf(2.f * u);
          const float th = (ex - 1.f) / (ex + 1.f);
          outb[(size_t)row * N + col] = f2bf(0.5f * v * (1.f + th));
        }
      }
    }
  }
}

// ---------------- flash attention (causal), 1 wave / 16 q-rows (R18-verified:
// XCD-locality decode + setprio) ----------------
__global__ __launch_bounds__(64) void attn_k(const u16* __restrict__ qkv, const u16* __restrict__ vT, u16* __restrict__ o16)
{
  __shared__ u16 P[16 * 40];
  const int bid = blockIdx.x;
  const int bh = bid & 63, qt = bid >> 6;
  const int h = bh & 15, b = bh >> 4;
  const int lane = threadIdx.x, lg = lane >> 4, lr = lane & 15;
  const int q0 = qt << 4;
  const u16* qrow  = qkv + (size_t)(b * 1024 + q0 + lr) * 6144 + h * 128;
  const u16* krow  = qkv + (size_t)(b * 1024 + lr) * 6144 + 2048 + h * 128;
  const u16* vbase = vT + (size_t)(b * 16 + h) * 128 * 1024;

  bf16x8 qf[4];
#pragma unroll
  for (int c = 0; c < 4; ++c) qf[c] = *(const bf16x8*)(qrow + c * 32 + lg * 8);

  float m[4], l[4];
  f32x4 oacc[8];
#pragma unroll
  for (int r = 0; r < 4; ++r){ m[r] = -1e30f; l[r] = 0.f; }
#pragma unroll
  for (int f = 0; f < 8; ++f)
#pragma unroll
    for (int r = 0; r < 4; ++r) oacc[f][r] = 0.f;

  const float scale = 0.08838834764831845f;
  const int nk2 = (qt >> 1) + 1;
  for (int k2 = 0; k2 < nk2; ++k2){
    float e[2][4];
    float rmax[4];
#pragma unroll
    for (int r = 0; r < 4; ++r) rmax[r] = -1e30f;
#pragma unroll
    for (int hh = 0; hh < 2; ++hh){
      const int kt = k2 * 2 + hh;
      if (kt <= qt){
        f32x4 s;
#pragma unroll
        for (int r = 0; r < 4; ++r) s[r] = 0.f;
        __builtin_amdgcn_s_setprio(1);
#pragma unroll
        for (int c = 0; c < 4; ++c){
          bf16x8 kf = *(const bf16x8*)(krow + (size_t)(kt * 16) * 6144 + c * 32 + lg * 8);
          s = __builtin_amdgcn_mfma_f32_16x16x32_bf16(qf[c], kf, s, 0, 0, 0);
        }
        __builtin_amdgcn_s_setprio(0);
#pragma unroll
        for (int r = 0; r < 4; ++r){
          float sv = s[r] * scale;
          if (kt * 16 + lr > q0 + lg * 4 + r) sv = -1e30f;
          e[hh][r] = sv;
          rmax[r] = fmaxf(rmax[r], sv);
        }
      } else {
#pragma unroll
        for (int r = 0; r < 4; ++r) e[hh][r] = -1e30f;
      }
    }
#pragma unroll
    for (int off = 8; off >= 1; off >>= 1)
#pragma unroll
      for (int r = 0; r < 4; ++r) rmax[r] = fmaxf(rmax[r], __shfl_xor(rmax[r], off));
    float corr[4], rsum[4];
#pragma unroll
    for (int r = 0; r < 4; ++r){
      const float mn = fmaxf(m[r], rmax[r]);
      corr[r] = __expf(m[r] - mn);
      m[r] = mn;
      const float e0 = __expf(e[0][r] - mn);
      const float e1 = __expf(e[1][r] - mn);
      e[0][r] = e0; e[1][r] = e1;
      rsum[r] = e0 + e1;
    }
#pragma unroll
    for (int off = 8; off >= 1; off >>= 1)
#pragma unroll
      for (int r = 0; r < 4; ++r) rsum[r] += __shfl_xor(rsum[r], off);
#pragma unroll
    for (int r = 0; r < 4; ++r) l[r] = l[r] * corr[r] + rsum[r];
#pragma unroll
    for (int hh = 0; hh < 2; ++hh)
#pragma unroll
      for (int r = 0; r < 4; ++r)
        P[(lg * 4 + r) * 40 + hh * 16 + lr] = f2bf(e[hh][r]);
#pragma unroll
    for (int f = 0; f < 8; ++f)
#pragma unroll
      for (int r = 0; r < 4; ++r) oacc[f][r] = oacc[f][r] * corr[r];
    __syncthreads();
    const bf16x8 pa = *(const bf16x8*)((const u16*)P + lr * 40 + lg * 8);
    __builtin_amdgcn_s_setprio(1);
#pragma unroll
    for (int f = 0; f < 8; ++f){
      bf16x8 vb = *(const bf16x8*)(vbase + (size_t)(f * 16 + lr) * 1024 + k2 * 32 + lg * 8);
      oacc[f] = __builtin_amdgcn_mfma_f32_16x16x32_bf16(pa, vb, oacc[f], 0, 0, 0);
    }
    __builtin_amdgcn_s_setprio(0);
    __syncthreads();
  }
  u16* orow = o16 + (size_t)(b * 1024 + q0 + lg * 4) * 2048 + h * 128;
#pragma unroll
  for (int r = 0; r < 4; ++r){
    const float linv = 1.0f / l[r];
#pragma unroll
    for (int f = 0; f < 8; ++f)
      orow[(size_t)r * 2048 + f * 16 + lr] = f2bf(oacc[f][r] * linv);
  }
}

// ---------------- logsumexp finalize + surprisal ----------------
__global__ __launch_bounds__(256) void lse_k(const float* __restrict__ partial, const float* __restrict__ tokl,
                                             const int* __restrict__ amask, float* __restrict__ surp)
{
  const int row = blockIdx.x, t = threadIdx.x, lane = t & 63, wid = t >> 6;
  float s = 0.f;
  if (t < 250) s = partial[(size_t)row * 500 + t] + partial[(size_t)row * 500 + t + 250];
#pragma unroll
  for (int off = 32; off >= 1; off >>= 1) s += __shfl_down(s, off);
  __shared__ float rb[4];
  if (lane == 0) rb[wid] = s;
  __syncthreads();
  if (t == 0){
    const float tot = rb[0] + rb[1] + rb[2] + rb[3];
    surp[row] = (logf(tot) - tokl[row]) * 1.4426950408889634f * (float)amask[row];
  }
}

// ---------------- mean-pool over sequence ----------------
__global__ __launch_bounds__(256) void pool_k(const u16* __restrict__ h16, float* __restrict__ pooled)
{
  const int d = blockIdx.x * 256 + threadIdx.x;
  const int b = blockIdx.y;
  const u16* p = h16 + (size_t)b * 1024 * 2048 + d;
  float a0 = 0.f, a1 = 0.f, a2 = 0.f, a3 = 0.f;
  for (int s = 0; s < 1024; s += 4){
    a0 += bf2f(p[(size_t)(s + 0) * 2048]);
    a1 += bf2f(p[(size_t)(s + 1) * 2048]);
    a2 += bf2f(p[(size_t)(s + 2) * 2048]);
    a3 += bf2f(p[(size_t)(s + 3) * 2048]);
  }
  pooled[b * 2048 + d] = (a0 + a1 + a2 + a3) * (1.f / 1024.f);
}

// ---------------- classifier head ----------------
__global__ __launch_bounds__(256) void cls_k(const float* __restrict__ pooled, const float* __restrict__ surp,
                                             const int* __restrict__ amask, const float* __restrict__ sent,
                                             const float* __restrict__ ppl, const float* __restrict__ redw,
                                             const float* __restrict__ redb, const float* __restrict__ clsw,
                                             const float* __restrict__ clsb, float* __restrict__ out)
{
  const int b = blockIdx.x, t = threadIdx.x;
  const int lane = t & 63, wid = t >> 6;
  __shared__ float pl[2048];
  __shared__ float feats[112];
  __shared__ float rbuf[2][4];
#pragma unroll
  for (int i = 0; i < 8; ++i) pl[t + i * 256] = pooled[b * 2048 + t + i * 256];
  float ssum = 0.f, msum = 0.f;
#pragma unroll
  for (int i = 0; i < 4; ++i){
    const int s = t + i * 256;
    ssum += surp[b * 1024 + s];
    msum += (float)amask[b * 1024 + s];
  }
#pragma unroll
  for (int off = 32; off >= 1; off >>= 1){ ssum += __shfl_down(ssum, off); msum += __shfl_down(msum, off); }
  if (lane == 0){ rbuf[0][wid] = ssum; rbuf[1][wid] = msum; }
  __syncthreads();
  if (t == 0){
    float a = 0.f, c = 0.f;
    for (int i = 0; i < 4; ++i){ a += rbuf[0][i]; c += rbuf[1][i]; }
    feats[104] = a / c;
  }
  if (t >= 100 && t < 103) feats[t] = sent[b * 3 + (t - 100)];
  if (t == 103) feats[103] = ppl[b];
  if (t < 100){
    float a = redb[t];
    for (int d = 0; d < 2048; ++d) a += pl[d] * redw[d * 100 + t];
    feats[t] = (a > 0.f) ? a : 0.01f * a;
  }
  __syncthreads();
  if (t < 3){
    float a = clsb[t];
    for (int i = 0; i < 105; ++i) a += feats[i] * clsw[i * 3 + t];
    out[b * 3 + t] = a;
  }
}

// ---------------- host launch ----------------
extern "C" void kernel_launch(void* const* d_in, const int* in_sizes, int n_in,
                              void* d_out, int out_size, void* d_ws, size_t ws_size,
                              hipStream_t stream)
{
  (void)in_sizes; (void)n_in; (void)out_size; (void)ws_size;
  const int*   ids   = (const int*)d_in[0];
  const int*   amask = (const int*)d_in[1];
  const float* sent  = (const float*)d_in[2];
  const float* ppl   = (const float*)d_in[3];
  const float* emb   = (const float*)d_in[4];
  const float* ln1g  = (const float*)d_in[5];
  const float* ln1b  = (const float*)d_in[6];
  const float* qkvw  = (const float*)d_in[7];
  const float* wow   = (const float*)d_in[8];
  const float* ln2g  = (const float*)d_in[9];
  const float* ln2b  = (const float*)d_in[10];
  const float* w1    = (const float*)d_in[11];
  const float* w2    = (const float*)d_in[12];
  const float* lnfg  = (const float*)d_in[13];
  const float* lnfb  = (const float*)d_in[14];
  const float* headw = (const float*)d_in[15];
  const float* redw  = (const float*)d_in[16];
  const float* redb  = (const float*)d_in[17];
  const float* clsw  = (const float*)d_in[18];
  const float* clsb  = (const float*)d_in[19];
  float* out = (float*)d_out;

  char* p = (char*)d_ws;
  u16* wqkvT = (u16*)p; p += (size_t)2 * 6144 * 2048 * 2;
  u16* woT   = (u16*)p; p += (size_t)2 * 2048 * 2048 * 2;
  u8*  w18   = (u8*)p;  p += (size_t)2 * 8192 * 2048;
  u16* w2T   = (u16*)p; p += (size_t)2 * 2048 * 8192 * 2;
  u8*  wh8   = (u8*)p;  p += (size_t)32000 * 2048;
  float* xbuf = (float*)p; p += (size_t)4096 * 2048 * 4;
  u16* h16   = (u16*)p; p += (size_t)4096 * 2048 * 2;
  u8*  h8    = (u8*)p;  p += (size_t)4096 * 2048;
  u16* qkv16 = (u16*)p;
  u16* vT16  = (u16*)(p + (size_t)4096 * 6144 * 2);
  u16* ffn16 = (u16*)p;
  p += (size_t)4096 * 6144 * 2 + (size_t)4096 * 2048 * 2;
  u16* o16   = (u16*)p; p += (size_t)4096 * 2048 * 2;
  float* partial = (float*)p; p += (size_t)4096 * 500 * 4;
  float* tokl = (float*)p; p += (size_t)4096 * 4;
  float* surp = (float*)p; p += (size_t)4096 * 4;
  float* pooled = (float*)p; p += (size_t)4 * 2048 * 4;

  for (int l = 0; l < 2; ++l){
    transp_k<<<dim3(6144/64, 2048/64), 256, 0, stream>>>(qkvw + (size_t)l*2048*6144, wqkvT + (size_t)l*6144*2048, 2048, 6144);
    transp_k<<<dim3(2048/64, 2048/64), 256, 0, stream>>>(wow  + (size_t)l*2048*2048, woT   + (size_t)l*2048*2048, 2048, 2048);
    transp8_k<<<dim3(8192/64, 2048/64), 256, 0, stream>>>(w1   + (size_t)l*2048*8192, w18   + (size_t)l*8192*2048, 2048, 8192);
    transp_k<<<dim3(2048/64, 8192/64), 256, 0, stream>>>(w2   + (size_t)l*8192*2048, w2T   + (size_t)l*2048*8192, 8192, 2048);
  }
  transp8_k<<<dim3(32000/64, 2048/64), 256, 0, stream>>>(headw, wh8, 2048, 32000);

  embed_k<<<dim3(4096, 8), 256, 0, stream>>>(ids, emb, xbuf);

  for (int l = 0; l < 2; ++l){
    ln_k<0><<<4096, 256, 0, stream>>>(xbuf, ln1g + l*2048, ln1b + l*2048, h16, nullptr);
    gemm6_k<M_QKV><<<16*24, 512, 0, stream>>>(h16, wqkvT + (size_t)l*6144*2048, 6144, 2048, 16,
                                              qkv16, nullptr, vT16);
    attn_k<<<4096, 64, 0, stream>>>(qkv16, vT16, o16);
    gemm2_k<M_RES,128><<<32*8, 512, 0, stream>>>(o16, woT + (size_t)l*2048*2048, 2048, 2048, 32,
                                                 nullptr, xbuf);
    ln_k<1><<<4096, 256, 0, stream>>>(xbuf, ln2g + l*2048, ln2b + l*2048, nullptr, h8);
    gemm8_k<M_GELU><<<16*32, 512, 0, stream>>>(h8, w18 + (size_t)l*8192*2048, 8192, 2048, 16,
                                               ffn16, nullptr, nullptr, nullptr);
    gemm2_k<M_RES,128><<<32*8, 512, 0, stream>>>(ffn16, w2T + (size_t)l*2048*8192, 2048, 8192, 32,
                                                 nullptr, xbuf);
  }
  ln_k<2><<<4096, 256, 0, stream>>>(xbuf, lnfg, lnfb, h16, h8);
  gemm8_k<M_LSE><<<16*125, 512, 0, stream>>>(h8, wh8, 32000, 2048, 16,
                                             nullptr, partial, tokl, ids);
  lse_k<<<4096, 256, 0, stream>>>(partial, tokl, amask, surp);
  pool_k<<<dim3(8, 4), 256, 0, stream>>>(h16, pooled);
  cls_k<<<4, 256, 0, stream>>>(pooled, surp, amask, sent, ppl, redw, redb, clsw, clsb, out);
}